// Round 1
// baseline (2003.291 us; speedup 1.0000x reference)
//
#include <hip/hip_runtime.h>

#define RP 16
#define EMB 16
#define NC 40

// ---------------------------------------------------------------------------
// Stage 1: latents[t, k] = sum over COO entries (rm_rows, rm_cols, rm_vals)
//          of vals * rel_emb[col, k]
// One thread per (entry, k).
__global__ void k_latents(const float* __restrict__ rel_emb,
                          const int* __restrict__ rows,
                          const int* __restrict__ cols,
                          const float* __restrict__ vals,
                          float* __restrict__ latents, int nm) {
    int i = blockIdx.x * blockDim.x + threadIdx.x;
    int e = i >> 4, k = i & 15;
    if (e < nm) {
        atomicAdd(&latents[rows[e] * RP + k], vals[e] * rel_emb[cols[e] * RP + k]);
    }
}

// ---------------------------------------------------------------------------
// Stage 2: row softmax over the 16 rp slots. 16 lanes per row.
__global__ void k_softmax(float* __restrict__ latents, int nt) {
    int i = blockIdx.x * blockDim.x + threadIdx.x;
    int t = i >> 4;
    if (t >= nt) return;
    float v = latents[i];
    float m = v;
    #pragma unroll
    for (int d = 1; d < 16; d <<= 1) m = fmaxf(m, __shfl_xor(m, d, 16));
    v = expf(v - m);
    float s = v;
    #pragma unroll
    for (int d = 1; d < 16; d <<= 1) s += __shfl_xor(s, d, 16);
    latents[i] = v / s;
}

// ---------------------------------------------------------------------------
// Stage 3a: r == 0 slice — h_cols and v_rows are all 0 there, so
// colsum[0] and rowsum[0] each get sum_t latents[t,0]. Grid reduction.
__global__ void k_r0sum(const float* __restrict__ latents,
                        float* __restrict__ colsum,
                        float* __restrict__ rowsum, int nt) {
    float acc = 0.f;
    for (int t = blockIdx.x * blockDim.x + threadIdx.x; t < nt;
         t += gridDim.x * blockDim.x)
        acc += latents[t * RP];   // r = 0
    // wave reduce (64 lanes)
    #pragma unroll
    for (int d = 32; d; d >>= 1) acc += __shfl_down(acc, d, 64);
    __shared__ float sm[4];
    int lane = threadIdx.x & 63, wid = threadIdx.x >> 6;
    if (lane == 0) sm[wid] = acc;
    __syncthreads();
    if (threadIdx.x == 0) {
        float tot = sm[0] + sm[1] + sm[2] + sm[3];
        atomicAdd(&colsum[0], tot);
        atomicAdd(&rowsum[0], tot);
    }
}

// Stage 3b: r >= 1 entries, direct atomics (targets well spread).
__global__ void k_sums(const float* __restrict__ latents,
                       const int* __restrict__ h_cols,
                       const int* __restrict__ v_rows,
                       float* __restrict__ colsum,
                       float* __restrict__ rowsum, int nt, int ne) {
    int e = nt + blockIdx.x * blockDim.x + threadIdx.x;
    if (e >= ne) return;
    int t = e % nt, r = e / nt;
    float lf = latents[t * RP + r];
    atomicAdd(&colsum[h_cols[e]], lf);
    atomicAdd(&rowsum[v_rows[e]], lf);
}

// ---------------------------------------------------------------------------
// Stage 4: h[s, k] += sum_r (lf_r / colsum[o*r]) * w1[(o*r), k]
// 16 lanes per pair t; lane k holds ln for r=k, shuffled around the group.
__global__ void k_h(const float* __restrict__ latents,
                    const int* __restrict__ h_rows,   // [t] -> s_u
                    const int* __restrict__ v_cols,   // [t] -> o_u
                    const float* __restrict__ colsum,
                    const float* __restrict__ w1,     // (rp*n, EMB)
                    float* __restrict__ h, int nt) {
    int i = blockIdx.x * blockDim.x + threadIdx.x;
    int t = i >> 4, k = i & 15;
    if (t >= nt) return;
    int s = h_rows[t];
    int o = v_cols[t];
    float lf = latents[t * RP + k];          // coalesced within group
    float ln_k = lf / colsum[o * k];         // h_cols[k*nt+t] == o*k
    float acc = 0.f;
    #pragma unroll
    for (int r = 0; r < RP; ++r) {
        float lnr = __shfl(ln_k, r, 16);
        acc += lnr * w1[(o * r) * EMB + k];
    }
    atomicAdd(&h[s * EMB + k], acc);
}

// ---------------------------------------------------------------------------
// Stage 5: h = relu(h + bias1)
__global__ void k_relu(float* __restrict__ h, const float* __restrict__ bias1,
                       int n16) {
    int i = blockIdx.x * blockDim.x + threadIdx.x;
    if (i < n16) h[i] = fmaxf(h[i] + bias1[i & 15], 0.f);
}

// ---------------------------------------------------------------------------
// Stage 6: h2[s*r, k] += (lf_r / rowsum[s*r]) * h[o, k]
// 16 lanes per pair t. r==0 target is row 0 for every t -> block-reduce in LDS.
__global__ void k_h2(const float* __restrict__ latents,
                     const int* __restrict__ h_rows,
                     const int* __restrict__ v_cols,
                     const float* __restrict__ rowsum,
                     const float* __restrict__ h,
                     float* __restrict__ h2, int nt) {
    __shared__ float r0acc[EMB];
    if (threadIdx.x < EMB) r0acc[threadIdx.x] = 0.f;
    __syncthreads();
    int i = blockIdx.x * blockDim.x + threadIdx.x;
    int t = i >> 4, k = i & 15;
    bool active = (t < nt);
    int s = 0;
    float hv = 0.f, ln2_k = 0.f;
    if (active) {
        s = h_rows[t];
        int o = v_cols[t];
        hv = h[o * EMB + k];
        float lf = latents[t * RP + k];
        ln2_k = lf / rowsum[s * k];          // v_rows[k*nt+t] == s*k
    }
    float ln20 = __shfl(ln2_k, 0, 16);
    if (active) atomicAdd(&r0acc[k], ln20 * hv);
    #pragma unroll
    for (int r = 1; r < RP; ++r) {
        float lnr = __shfl(ln2_k, r, 16);
        if (active) atomicAdd(&h2[(s * r) * EMB + k], lnr * hv);
    }
    __syncthreads();
    if (threadIdx.x < EMB) atomicAdd(&h2[threadIdx.x], r0acc[threadIdx.x]);
}

// ---------------------------------------------------------------------------
// Stage 7: out[node, c] = bias2[c] + sum_rq sum_h w2[rq,h,c] * h2[rq*n+node, h]
__global__ void k_out(const float* __restrict__ w2,
                      const float* __restrict__ bias2,
                      const float* __restrict__ h2,
                      float* __restrict__ out, int n) {
    int i = blockIdx.x * blockDim.x + threadIdx.x;
    int node = i / NC, c = i - node * NC;
    if (node >= n) return;
    float acc = bias2[c];
    #pragma unroll 4
    for (int rq = 0; rq < RP; ++rq) {
        const float* h2row = &h2[(rq * n + node) * EMB];
        const float* w2r = &w2[rq * EMB * NC + c];
        #pragma unroll
        for (int hh = 0; hh < EMB; ++hh)
            acc += w2r[hh * NC] * h2row[hh];
    }
    out[node * NC + c] = acc;
}

// ---------------------------------------------------------------------------
extern "C" void kernel_launch(void* const* d_in, const int* in_sizes, int n_in,
                              void* d_out, int out_size, void* d_ws, size_t ws_size,
                              hipStream_t stream) {
    const float* rel_emb = (const float*)d_in[0];
    const float* w1      = (const float*)d_in[1];
    const float* w2      = (const float*)d_in[2];
    const float* b1      = (const float*)d_in[3];
    const float* b2      = (const float*)d_in[4];
    const int*   rm_rows = (const int*)d_in[5];
    const int*   rm_cols = (const int*)d_in[6];
    const float* rm_vals = (const float*)d_in[7];
    const int*   h_rows  = (const int*)d_in[8];
    // d_in[9] = h_cols, d_in[10] = v_rows used only in k_sums
    const int*   h_cols  = (const int*)d_in[9];
    const int*   v_rows  = (const int*)d_in[10];
    const int*   v_cols  = (const int*)d_in[11];

    const int nm = in_sizes[5];
    const int ne = in_sizes[8];
    const int nt = ne / RP;
    const int n  = in_sizes[1] / (RP * EMB);

    float* latents = (float*)d_ws;                       // nt*16
    float* colsum  = latents + (size_t)nt * RP;          // n*16
    float* rowsum  = colsum + (size_t)n * RP;            // n*16
    float* h       = rowsum + (size_t)n * RP;            // n*16
    float* h2      = h + (size_t)n * EMB;                // n*256

    size_t need_floats = (size_t)nt * RP + (size_t)n * RP * 2 +
                         (size_t)n * EMB + (size_t)n * RP * EMB;
    if (ws_size < need_floats * sizeof(float)) return;   // fail loud via mismatch

    hipMemsetAsync(d_ws, 0, need_floats * sizeof(float), stream);

    const int B = 256;
    // 1. latents accumulation
    {
        long long th = (long long)nm * RP;
        k_latents<<<dim3((th + B - 1) / B), dim3(B), 0, stream>>>(
            rel_emb, rm_rows, rm_cols, rm_vals, latents, nm);
    }
    // 2. softmax
    k_softmax<<<dim3((ne + B - 1) / B), dim3(B), 0, stream>>>(latents, nt);
    // 3. normalizer sums
    k_r0sum<<<dim3(512), dim3(B), 0, stream>>>(latents, colsum, rowsum, nt);
    {
        int th = ne - nt;
        k_sums<<<dim3((th + B - 1) / B), dim3(B), 0, stream>>>(
            latents, h_cols, v_rows, colsum, rowsum, nt, ne);
    }
    // 4. first spmm -> h
    k_h<<<dim3((ne + B - 1) / B), dim3(B), 0, stream>>>(
        latents, h_rows, v_cols, colsum, w1, h, nt);
    // 5. bias + relu
    k_relu<<<dim3((n * EMB + B - 1) / B), dim3(B), 0, stream>>>(h, b1, n * EMB);
    // 6. second spmm -> h2
    k_h2<<<dim3((ne + B - 1) / B), dim3(B), 0, stream>>>(
        latents, h_rows, v_cols, rowsum, h, h2, nt);
    // 7. final einsum -> out
    k_out<<<dim3((n * NC + B - 1) / B), dim3(B), 0, stream>>>(
        w2, b2, h2, (float*)d_out, n);
}

// Round 2
// 624.941 us; speedup vs baseline: 3.2056x; 3.2056x over previous
//
#include <hip/hip_runtime.h>

#define RP 16
#define EMB 16
#define NC 40

// ---------------------------------------------------------------------------
// Stage 1+2: latents[t,:] = segment-sum over sorted rm_rows, then softmax.
// rm_rows is non-decreasing (np.unique output) -> leader-scan, no atomics.
// 16 lanes per COO entry; only row-leader groups write.
__global__ void k_latents(const float* __restrict__ rel_emb,
                          const int* __restrict__ rows,
                          const int* __restrict__ cols,
                          const float* __restrict__ vals,
                          float* __restrict__ latents, int nm) {
    int i = blockIdx.x * blockDim.x + threadIdx.x;
    int e = i >> 4, k = i & 15;
    if (e >= nm) return;
    int row = rows[e];
    if (e > 0 && rows[e - 1] == row) return;          // not a row leader
    float acc = vals[e] * rel_emb[cols[e] * RP + k];
    while (e + 1 < nm && rows[e + 1] == row) {
        ++e;
        acc += vals[e] * rel_emb[cols[e] * RP + k];
    }
    // inline 16-lane softmax
    float m = acc;
    #pragma unroll
    for (int d = 1; d < 16; d <<= 1) m = fmaxf(m, __shfl_xor(m, d, 16));
    float v = expf(acc - m);
    float s = v;
    #pragma unroll
    for (int d = 1; d < 16; d <<= 1) s += __shfl_xor(s, d, 16);
    latents[row * RP + k] = v / s;
}

// ---------------------------------------------------------------------------
// Bucket build: counts per s (h_rows[0:nt]) and per o (v_cols[0:nt]).
__global__ void k_count(const int* __restrict__ s_u, const int* __restrict__ o_u,
                        int* __restrict__ cnt_s, int* __restrict__ cnt_o, int nt) {
    int t = blockIdx.x * blockDim.x + threadIdx.x;
    if (t < nt) {
        atomicAdd(&cnt_s[s_u[t]], 1);
        atomicAdd(&cnt_o[o_u[t]], 1);
    }
}

// Exclusive scan of two n-length arrays; block 0 scans s, block 1 scans o.
// Writes both offs (stable) and cur (scatter cursors).
__global__ void k_scan(const int* __restrict__ cnt_s, int* __restrict__ offs_s,
                       int* __restrict__ cur_s,
                       const int* __restrict__ cnt_o, int* __restrict__ offs_o,
                       int* __restrict__ cur_o, int n) {
    const int* in = blockIdx.x ? cnt_o : cnt_s;
    int* out = blockIdx.x ? offs_o : offs_s;
    int* cur = blockIdx.x ? cur_o : cur_s;
    __shared__ int wsum[16];
    __shared__ int carrysh;
    int lane = threadIdx.x & 63, wid = threadIdx.x >> 6;
    if (threadIdx.x == 0) carrysh = 0;
    __syncthreads();
    for (int base = 0; base < n; base += 1024) {
        int i = base + threadIdx.x;
        int v = (i < n) ? in[i] : 0;
        int x = v;
        #pragma unroll
        for (int d = 1; d < 64; d <<= 1) {
            int u = __shfl_up(x, d, 64);
            if (lane >= d) x += u;
        }
        if (lane == 63) wsum[wid] = x;
        __syncthreads();
        if (wid == 0 && lane < 16) {
            int w = wsum[lane];
            int y = w;
            #pragma unroll
            for (int d = 1; d < 16; d <<= 1) {
                int u = __shfl_up(y, d, 16);
                if (lane >= d) y += u;
            }
            wsum[lane] = y - w;                       // exclusive wave offsets
        }
        __syncthreads();
        int excl = carrysh + wsum[wid] + x - v;
        if (i < n) { out[i] = excl; cur[i] = excl; }
        __syncthreads();
        if (threadIdx.x == 1023) carrysh += wsum[15] + x;
        __syncthreads();
    }
}

__global__ void k_scatter(const int* __restrict__ s_u, const int* __restrict__ o_u,
                          int* __restrict__ cur_s, int* __restrict__ cur_o,
                          int* __restrict__ bkt_s, int* __restrict__ bkt_o, int nt) {
    int t = blockIdx.x * blockDim.x + threadIdx.x;
    if (t < nt) {
        bkt_s[atomicAdd(&cur_s[s_u[t]], 1)] = t;
        bkt_o[atomicAdd(&cur_o[o_u[t]], 1)] = t;
    }
}

// ---------------------------------------------------------------------------
// Stage 3: per-node latent sums -> rowsum (via s buckets) / colsum (via o).
// Group (16 lanes) per node v: ls_r = sum_{t in bucket(v)} latents[t,r].
// Lane r>=1 adds into dst[v*r]; r==0 contributions block-reduced into dst[0].
__global__ void k_latsum(const float* __restrict__ latents,
                         const int* __restrict__ bkt,
                         const int* __restrict__ offs,
                         const int* __restrict__ cnt,
                         float* __restrict__ dst, int n) {
    __shared__ float r0s;
    if (threadIdx.x == 0) r0s = 0.f;
    __syncthreads();
    int i = blockIdx.x * blockDim.x + threadIdx.x;
    int v = i >> 4, k = i & 15;
    float ls = 0.f;
    if (v < n) {
        int beg = offs[v], d = cnt[v];
        for (int j = 0; j < d; ++j) {
            int t = bkt[beg + j];
            ls += latents[t * RP + k];
        }
        if (k >= 1 && ls != 0.f) atomicAdd(&dst[v * k], ls);
        if (k == 0 && ls != 0.f) atomicAdd(&r0s, ls);
    }
    __syncthreads();
    if (threadIdx.x == 0 && r0s != 0.f) atomicAdd(&dst[0], r0s);
}

// ---------------------------------------------------------------------------
// Stage 4+5: h[s,k] = relu(bias1[k] + sum_{t in S(s)} sum_r ln[t,r]*w1[o_t*r, k])
// where ln[t,r] = latents[t,r]/colsum[o_t*r]. No atomics: one group owns s.
__global__ void k_h(const float* __restrict__ latents,
                    const int* __restrict__ bkt_s,
                    const int* __restrict__ offs_s,
                    const int* __restrict__ cnt_s,
                    const int* __restrict__ o_u,
                    const float* __restrict__ colsum,
                    const float* __restrict__ w1,
                    const float* __restrict__ bias1,
                    float* __restrict__ h, int n) {
    int i = blockIdx.x * blockDim.x + threadIdx.x;
    int s = i >> 4, k = i & 15;
    if (s >= n) return;
    int beg = offs_s[s], d = cnt_s[s];
    float acc = 0.f;
    for (int j = 0; j < d; ++j) {
        int t = bkt_s[beg + j];
        int o = o_u[t];
        float lat = latents[t * RP + k];
        float ln = lat / colsum[o * k];               // k=0 -> colsum[0]
        #pragma unroll
        for (int r = 0; r < RP; ++r) {
            float lnr = __shfl(ln, r, 16);
            acc += lnr * w1[(size_t)(o * r) * EMB + k];
        }
    }
    h[s * EMB + k] = fmaxf(acc + bias1[k], 0.f);
}

// ---------------------------------------------------------------------------
// Stage 6: per-s outer-product accumulation M[k][r] = sum_t h[o_t,k]*lat[t,r],
// then h2[s*r, k] += M[k][r]/rowsum[s*r] (15 aliased atomics per lane),
// r==0 (all nodes -> row 0) block-reduced in LDS.
__global__ void k_h2(const float* __restrict__ latents,
                     const int* __restrict__ bkt_s,
                     const int* __restrict__ offs_s,
                     const int* __restrict__ cnt_s,
                     const int* __restrict__ o_u,
                     const float* __restrict__ rowsum,
                     const float* __restrict__ h,
                     float* __restrict__ h2, int n) {
    __shared__ float r0acc[EMB];
    if (threadIdx.x < EMB) r0acc[threadIdx.x] = 0.f;
    __syncthreads();
    int i = blockIdx.x * blockDim.x + threadIdx.x;
    int s = i >> 4, k = i & 15;
    float M[RP];
    #pragma unroll
    for (int r = 0; r < RP; ++r) M[r] = 0.f;
    int d = 0;
    if (s < n) {
        int beg = offs_s[s];
        d = cnt_s[s];
        for (int j = 0; j < d; ++j) {
            int t = bkt_s[beg + j];
            int o = o_u[t];
            float hv = h[o * EMB + k];
            float lat = latents[t * RP + k];
            #pragma unroll
            for (int r = 0; r < RP; ++r)
                M[r] += __shfl(lat, r, 16) * hv;
        }
    }
    if (s < n && d > 0) {
        float rs = rowsum[s * k];                     // lane k: rowsum[s*k]
        float rs0 = __shfl(rs, 0, 16);
        atomicAdd(&r0acc[k], M[0] / rs0);
        #pragma unroll
        for (int r = 1; r < RP; ++r) {
            float rsr = __shfl(rs, r, 16);
            atomicAdd(&h2[(size_t)(s * r) * EMB + k], M[r] / rsr);
        }
    }
    __syncthreads();
    if (threadIdx.x < EMB) {
        float v = r0acc[threadIdx.x];
        if (v != 0.f) atomicAdd(&h2[threadIdx.x], v);
    }
}

// ---------------------------------------------------------------------------
// Stage 7: out[node,c] = bias2[c] + sum_rq sum_h w2[rq,h,c]*h2[rq*n+node, h]
__global__ void k_out(const float* __restrict__ w2,
                      const float* __restrict__ bias2,
                      const float* __restrict__ h2,
                      float* __restrict__ out, int n) {
    int i = blockIdx.x * blockDim.x + threadIdx.x;
    int node = i / NC, c = i - node * NC;
    if (node >= n) return;
    float acc = bias2[c];
    #pragma unroll 4
    for (int rq = 0; rq < RP; ++rq) {
        const float* h2row = &h2[((size_t)rq * n + node) * EMB];
        const float* w2r = &w2[rq * EMB * NC + c];
        #pragma unroll
        for (int hh = 0; hh < EMB; ++hh)
            acc += w2r[hh * NC] * h2row[hh];
    }
    out[node * NC + c] = acc;
}

// ---------------------------------------------------------------------------
extern "C" void kernel_launch(void* const* d_in, const int* in_sizes, int n_in,
                              void* d_out, int out_size, void* d_ws, size_t ws_size,
                              hipStream_t stream) {
    const float* rel_emb = (const float*)d_in[0];
    const float* w1      = (const float*)d_in[1];
    const float* w2      = (const float*)d_in[2];
    const float* b1      = (const float*)d_in[3];
    const float* b2      = (const float*)d_in[4];
    const int*   rm_rows = (const int*)d_in[5];
    const int*   rm_cols = (const int*)d_in[6];
    const float* rm_vals = (const float*)d_in[7];
    const int*   h_rows  = (const int*)d_in[8];   // [0:nt] = s_u
    const int*   v_cols  = (const int*)d_in[11];  // [0:nt] = o_u

    const int nm = in_sizes[5];
    const int ne = in_sizes[8];
    const int nt = ne / RP;
    const int n  = in_sizes[1] / (RP * EMB);

    char* w = (char*)d_ws;
    float* colsum = (float*)w;  w += (size_t)n * RP * 4;
    float* rowsum = (float*)w;  w += (size_t)n * RP * 4;
    float* h2     = (float*)w;  w += (size_t)n * RP * EMB * 4;
    int* cnt_s    = (int*)w;    w += (size_t)n * 4;
    int* cnt_o    = (int*)w;    w += (size_t)n * 4;
    size_t zero_bytes = (size_t)(w - (char*)d_ws);
    float* latents = (float*)w; w += (size_t)nt * RP * 4;
    float* h       = (float*)w; w += (size_t)n * EMB * 4;
    int* offs_s    = (int*)w;   w += (size_t)n * 4;
    int* cur_s     = (int*)w;   w += (size_t)n * 4;
    int* offs_o    = (int*)w;   w += (size_t)n * 4;
    int* cur_o     = (int*)w;   w += (size_t)n * 4;
    int* bkt_s     = (int*)w;   w += (size_t)nt * 4;
    int* bkt_o     = (int*)w;   w += (size_t)nt * 4;
    if ((size_t)(w - (char*)d_ws) > ws_size) return;

    hipMemsetAsync(d_ws, 0, zero_bytes, stream);

    const int B = 256;
    k_latents<<<dim3((nm * 16 + B - 1) / B), dim3(B), 0, stream>>>(
        rel_emb, rm_rows, rm_cols, rm_vals, latents, nm);
    k_count<<<dim3((nt + B - 1) / B), dim3(B), 0, stream>>>(
        h_rows, v_cols, cnt_s, cnt_o, nt);
    k_scan<<<dim3(2), dim3(1024), 0, stream>>>(
        cnt_s, offs_s, cur_s, cnt_o, offs_o, cur_o, n);
    k_scatter<<<dim3((nt + B - 1) / B), dim3(B), 0, stream>>>(
        h_rows, v_cols, cur_s, cur_o, bkt_s, bkt_o, nt);
    k_latsum<<<dim3((n * 16 + B - 1) / B), dim3(B), 0, stream>>>(
        latents, bkt_s, offs_s, cnt_s, rowsum, n);
    k_latsum<<<dim3((n * 16 + B - 1) / B), dim3(B), 0, stream>>>(
        latents, bkt_o, offs_o, cnt_o, colsum, n);
    k_h<<<dim3((n * 16 + B - 1) / B), dim3(B), 0, stream>>>(
        latents, bkt_s, offs_s, cnt_s, v_cols, colsum, w1, b1, h, n);
    k_h2<<<dim3((n * 16 + B - 1) / B), dim3(B), 0, stream>>>(
        latents, bkt_s, offs_s, cnt_s, v_cols, rowsum, h, h2, n);
    k_out<<<dim3((n * NC + B - 1) / B), dim3(B), 0, stream>>>(
        w2, b2, h2, (float*)d_out, n);
}

// Round 3
// 508.393 us; speedup vs baseline: 3.9404x; 1.2292x over previous
//
#include <hip/hip_runtime.h>

#define RP 16
#define EMB 16
#define NC 40

// ---------------------------------------------------------------------------
// Stage 1+2: latents[t,:] = segment-sum over sorted rm_rows, then softmax.
__global__ void k_latents(const float* __restrict__ rel_emb,
                          const int* __restrict__ rows,
                          const int* __restrict__ cols,
                          const float* __restrict__ vals,
                          float* __restrict__ latents, int nm) {
    int i = blockIdx.x * blockDim.x + threadIdx.x;
    int e = i >> 4, k = i & 15;
    if (e >= nm) return;
    int row = rows[e];
    if (e > 0 && rows[e - 1] == row) return;          // not a row leader
    float acc = vals[e] * rel_emb[cols[e] * RP + k];
    while (e + 1 < nm && rows[e + 1] == row) {
        ++e;
        acc += vals[e] * rel_emb[cols[e] * RP + k];
    }
    float m = acc;
    #pragma unroll
    for (int d = 1; d < 16; d <<= 1) m = fmaxf(m, __shfl_xor(m, d, 16));
    float v = expf(acc - m);
    float s = v;
    #pragma unroll
    for (int d = 1; d < 16; d <<= 1) s += __shfl_xor(s, d, 16);
    latents[row * RP + k] = v / s;
}

// ---------------------------------------------------------------------------
// Bucket build.
__global__ void k_count(const int* __restrict__ s_u, const int* __restrict__ o_u,
                        int* __restrict__ cnt_s, int* __restrict__ cnt_o, int nt) {
    int t = blockIdx.x * blockDim.x + threadIdx.x;
    if (t < nt) {
        atomicAdd(&cnt_s[s_u[t]], 1);
        atomicAdd(&cnt_o[o_u[t]], 1);
    }
}

__global__ void k_scan(const int* __restrict__ cnt_s, int* __restrict__ offs_s,
                       int* __restrict__ cur_s,
                       const int* __restrict__ cnt_o, int* __restrict__ offs_o,
                       int* __restrict__ cur_o, int n) {
    const int* in = blockIdx.x ? cnt_o : cnt_s;
    int* out = blockIdx.x ? offs_o : offs_s;
    int* cur = blockIdx.x ? cur_o : cur_s;
    __shared__ int wsum[16];
    __shared__ int carrysh;
    int lane = threadIdx.x & 63, wid = threadIdx.x >> 6;
    if (threadIdx.x == 0) carrysh = 0;
    __syncthreads();
    for (int base = 0; base < n; base += 1024) {
        int i = base + threadIdx.x;
        int v = (i < n) ? in[i] : 0;
        int x = v;
        #pragma unroll
        for (int d = 1; d < 64; d <<= 1) {
            int u = __shfl_up(x, d, 64);
            if (lane >= d) x += u;
        }
        if (lane == 63) wsum[wid] = x;
        __syncthreads();
        if (wid == 0 && lane < 16) {
            int w = wsum[lane];
            int y = w;
            #pragma unroll
            for (int d = 1; d < 16; d <<= 1) {
                int u = __shfl_up(y, d, 16);
                if (lane >= d) y += u;
            }
            wsum[lane] = y - w;
        }
        __syncthreads();
        int excl = carrysh + wsum[wid] + x - v;
        if (i < n) { out[i] = excl; cur[i] = excl; }
        __syncthreads();
        if (threadIdx.x == 1023) carrysh += wsum[15] + x;
        __syncthreads();
    }
}

__global__ void k_scatter(const int* __restrict__ s_u, const int* __restrict__ o_u,
                          int* __restrict__ cur_s, int* __restrict__ cur_o,
                          int* __restrict__ bkt_s, int* __restrict__ bkt_o, int nt) {
    int t = blockIdx.x * blockDim.x + threadIdx.x;
    if (t < nt) {
        bkt_s[atomicAdd(&cur_s[s_u[t]], 1)] = t;
        bkt_o[atomicAdd(&cur_o[o_u[t]], 1)] = t;
    }
}

// ---------------------------------------------------------------------------
// Stage 3: per-node latent sums -> rowsum (s buckets) / colsum (o buckets).
__global__ void k_latsum(const float* __restrict__ latents,
                         const int* __restrict__ bkt,
                         const int* __restrict__ offs,
                         const int* __restrict__ cnt,
                         float* __restrict__ dst, int n) {
    __shared__ float r0s;
    if (threadIdx.x == 0) r0s = 0.f;
    __syncthreads();
    int i = blockIdx.x * blockDim.x + threadIdx.x;
    int v = i >> 4, k = i & 15;
    float ls = 0.f;
    if (v < n) {
        int beg = offs[v], d = cnt[v];
        for (int j = 0; j < d; ++j) {
            int t = bkt[beg + j];
            ls += latents[t * RP + k];
        }
        if (k >= 1 && ls != 0.f) atomicAdd(&dst[v * k], ls);
        if (k == 0 && ls != 0.f) atomicAdd(&r0s, ls);
    }
    __syncthreads();
    if (threadIdx.x == 0 && r0s != 0.f) atomicAdd(&dst[0], r0s);
}

// ---------------------------------------------------------------------------
// Stage 4: per-o accumulation. Group (16 lanes) owns node o: w1 rows o*r
// (r=0..15) live in registers (lane k holds W[r][k]); colsum[o*k] loaded once.
// For each pair t in O(o): c_k = sum_r ln[t,r]*W[r][k] -> atomicAdd h[s_t,k].
__global__ void k_h_acc(const float* __restrict__ latents,
                        const int* __restrict__ bkt_o,
                        const int* __restrict__ offs_o,
                        const int* __restrict__ cnt_o,
                        const int* __restrict__ s_u,
                        const float* __restrict__ colsum,
                        const float* __restrict__ w1,
                        float* __restrict__ h, int n) {
    int i = blockIdx.x * blockDim.x + threadIdx.x;
    int o = i >> 4, k = i & 15;
    if (o >= n) return;
    int d = cnt_o[o];
    if (d == 0) return;
    int beg = offs_o[o];
    float W[RP];
    #pragma unroll
    for (int r = 0; r < RP; ++r)
        W[r] = w1[(size_t)(o * r) * EMB + k];
    float rcp_cs = 1.f / colsum[o * k];
    for (int j = 0; j < d; ++j) {
        int t = bkt_o[beg + j];
        float ln = latents[t * RP + k] * rcp_cs;
        float acc = 0.f;
        #pragma unroll
        for (int r = 0; r < RP; ++r)
            acc += __shfl(ln, r, 16) * W[r];
        atomicAdd(&h[s_u[t] * EMB + k], acc);
    }
}

// Stage 5: h = relu(h + bias1)
__global__ void k_relu(float* __restrict__ h, const float* __restrict__ bias1,
                       int n16) {
    int i = blockIdx.x * blockDim.x + threadIdx.x;
    if (i < n16) h[i] = fmaxf(h[i] + bias1[i & 15], 0.f);
}

// ---------------------------------------------------------------------------
// Stage 6: per-s outer-product M[k][r] = sum_t h[o_t,k]*lat[t,r], then
// h2[s*r,k] += M[k][r]/rowsum[s*r]; r==0 block-reduced in LDS.
__global__ void k_h2(const float* __restrict__ latents,
                     const int* __restrict__ bkt_s,
                     const int* __restrict__ offs_s,
                     const int* __restrict__ cnt_s,
                     const int* __restrict__ o_u,
                     const float* __restrict__ rowsum,
                     const float* __restrict__ h,
                     float* __restrict__ h2, int n) {
    __shared__ float r0acc[EMB];
    if (threadIdx.x < EMB) r0acc[threadIdx.x] = 0.f;
    __syncthreads();
    int i = blockIdx.x * blockDim.x + threadIdx.x;
    int s = i >> 4, k = i & 15;
    float M[RP];
    #pragma unroll
    for (int r = 0; r < RP; ++r) M[r] = 0.f;
    int d = 0;
    if (s < n) {
        int beg = offs_s[s];
        d = cnt_s[s];
        for (int j = 0; j < d; ++j) {
            int t = bkt_s[beg + j];
            int o = o_u[t];
            float hv = h[o * EMB + k];
            float lat = latents[t * RP + k];
            #pragma unroll
            for (int r = 0; r < RP; ++r)
                M[r] += __shfl(lat, r, 16) * hv;
        }
    }
    if (s < n && d > 0) {
        float rs = rowsum[s * k];
        float rs0 = __shfl(rs, 0, 16);
        atomicAdd(&r0acc[k], M[0] / rs0);
        #pragma unroll
        for (int r = 1; r < RP; ++r) {
            float rsr = __shfl(rs, r, 16);
            atomicAdd(&h2[(size_t)(s * r) * EMB + k], M[r] / rsr);
        }
    }
    __syncthreads();
    if (threadIdx.x < EMB) {
        float v = r0acc[threadIdx.x];
        if (v != 0.f) atomicAdd(&h2[threadIdx.x], v);
    }
}

// ---------------------------------------------------------------------------
// Stage 7: thread = (node, 8-col block). acc[8] in regs; h2 rows read once
// per rq per 5 threads (L1-shared), coalesced across nodes.
#define CBLK 8
__global__ void k_out(const float* __restrict__ w2,
                      const float* __restrict__ bias2,
                      const float* __restrict__ h2,
                      float* __restrict__ out, int n) {
    int i = blockIdx.x * blockDim.x + threadIdx.x;
    int node = i / (NC / CBLK), cb = i % (NC / CBLK);
    if (node >= n) return;
    int c0 = cb * CBLK;
    float acc[CBLK];
    #pragma unroll
    for (int c = 0; c < CBLK; ++c) acc[c] = bias2[c0 + c];
    for (int rq = 0; rq < RP; ++rq) {
        const float4* h2row = (const float4*)&h2[((size_t)rq * n + node) * EMB];
        const float* w2r = &w2[(rq * EMB) * NC + c0];
        float4 hv4[4];
        #pragma unroll
        for (int q = 0; q < 4; ++q) hv4[q] = h2row[q];
        const float* hv = (const float*)hv4;
        #pragma unroll
        for (int hh = 0; hh < EMB; ++hh) {
            #pragma unroll
            for (int c = 0; c < CBLK; ++c)
                acc[c] += w2r[hh * NC + c] * hv[hh];
        }
    }
    #pragma unroll
    for (int c = 0; c < CBLK; ++c) out[node * NC + c0 + c] = acc[c];
}

// ---------------------------------------------------------------------------
extern "C" void kernel_launch(void* const* d_in, const int* in_sizes, int n_in,
                              void* d_out, int out_size, void* d_ws, size_t ws_size,
                              hipStream_t stream) {
    const float* rel_emb = (const float*)d_in[0];
    const float* w1      = (const float*)d_in[1];
    const float* w2      = (const float*)d_in[2];
    const float* b1      = (const float*)d_in[3];
    const float* b2      = (const float*)d_in[4];
    const int*   rm_rows = (const int*)d_in[5];
    const int*   rm_cols = (const int*)d_in[6];
    const float* rm_vals = (const float*)d_in[7];
    const int*   h_rows  = (const int*)d_in[8];   // [0:nt] = s_u
    const int*   v_cols  = (const int*)d_in[11];  // [0:nt] = o_u

    const int nm = in_sizes[5];
    const int ne = in_sizes[8];
    const int nt = ne / RP;
    const int n  = in_sizes[1] / (RP * EMB);

    char* w = (char*)d_ws;
    float* colsum = (float*)w;  w += (size_t)n * RP * 4;
    float* rowsum = (float*)w;  w += (size_t)n * RP * 4;
    float* h2     = (float*)w;  w += (size_t)n * RP * EMB * 4;
    float* h      = (float*)w;  w += (size_t)n * EMB * 4;
    int* cnt_s    = (int*)w;    w += (size_t)n * 4;
    int* cnt_o    = (int*)w;    w += (size_t)n * 4;
    size_t zero_bytes = (size_t)(w - (char*)d_ws);
    float* latents = (float*)w; w += (size_t)nt * RP * 4;
    int* offs_s    = (int*)w;   w += (size_t)n * 4;
    int* cur_s     = (int*)w;   w += (size_t)n * 4;
    int* offs_o    = (int*)w;   w += (size_t)n * 4;
    int* cur_o     = (int*)w;   w += (size_t)n * 4;
    int* bkt_s     = (int*)w;   w += (size_t)nt * 4;
    int* bkt_o     = (int*)w;   w += (size_t)nt * 4;
    if ((size_t)(w - (char*)d_ws) > ws_size) return;

    hipMemsetAsync(d_ws, 0, zero_bytes, stream);

    const int B = 256;
    k_latents<<<dim3((nm * 16 + B - 1) / B), dim3(B), 0, stream>>>(
        rel_emb, rm_rows, rm_cols, rm_vals, latents, nm);
    k_count<<<dim3((nt + B - 1) / B), dim3(B), 0, stream>>>(
        h_rows, v_cols, cnt_s, cnt_o, nt);
    k_scan<<<dim3(2), dim3(1024), 0, stream>>>(
        cnt_s, offs_s, cur_s, cnt_o, offs_o, cur_o, n);
    k_scatter<<<dim3((nt + B - 1) / B), dim3(B), 0, stream>>>(
        h_rows, v_cols, cur_s, cur_o, bkt_s, bkt_o, nt);
    k_latsum<<<dim3((n * 16 + B - 1) / B), dim3(B), 0, stream>>>(
        latents, bkt_s, offs_s, cnt_s, rowsum, n);
    k_latsum<<<dim3((n * 16 + B - 1) / B), dim3(B), 0, stream>>>(
        latents, bkt_o, offs_o, cnt_o, colsum, n);
    k_h_acc<<<dim3((n * 16 + B - 1) / B), dim3(B), 0, stream>>>(
        latents, bkt_o, offs_o, cnt_o, h_rows, colsum, w1, h, n);
    k_relu<<<dim3((n * EMB + B - 1) / B), dim3(B), 0, stream>>>(h, b1, n * EMB);
    k_h2<<<dim3((n * 16 + B - 1) / B), dim3(B), 0, stream>>>(
        latents, bkt_s, offs_s, cnt_s, v_cols, rowsum, h, h2, n);
    k_out<<<dim3((n * (NC / CBLK) + B - 1) / B), dim3(B), 0, stream>>>(
        w2, b2, h2, (float*)d_out, n);
}

// Round 4
// 413.950 us; speedup vs baseline: 4.8395x; 1.2282x over previous
//
#include <hip/hip_runtime.h>

#define RP 16
#define EMB 16
#define NC 40

// ---------------------------------------------------------------------------
// Stage 1+2: latents[t,:] = segment-sum over sorted rm_rows, then softmax.
__global__ void k_latents(const float* __restrict__ rel_emb,
                          const int* __restrict__ rows,
                          const int* __restrict__ cols,
                          const float* __restrict__ vals,
                          float* __restrict__ latents, int nm) {
    int i = blockIdx.x * blockDim.x + threadIdx.x;
    int e = i >> 4, k = i & 15;
    if (e >= nm) return;
    int row = rows[e];
    if (e > 0 && rows[e - 1] == row) return;          // not a row leader
    float acc = vals[e] * rel_emb[cols[e] * RP + k];
    while (e + 1 < nm && rows[e + 1] == row) {
        ++e;
        acc += vals[e] * rel_emb[cols[e] * RP + k];
    }
    float m = acc;
    #pragma unroll
    for (int d = 1; d < 16; d <<= 1) m = fmaxf(m, __shfl_xor(m, d, 16));
    float v = expf(acc - m);
    float s = v;
    #pragma unroll
    for (int d = 1; d < 16; d <<= 1) s += __shfl_xor(s, d, 16);
    latents[row * RP + k] = v / s;
}

// ---------------------------------------------------------------------------
// Bucket build.
__global__ void k_count(const int* __restrict__ s_u, const int* __restrict__ o_u,
                        int* __restrict__ cnt_s, int* __restrict__ cnt_o, int nt) {
    int t = blockIdx.x * blockDim.x + threadIdx.x;
    if (t < nt) {
        atomicAdd(&cnt_s[s_u[t]], 1);
        atomicAdd(&cnt_o[o_u[t]], 1);
    }
}

__global__ void k_scan(const int* __restrict__ cnt_s, int* __restrict__ offs_s,
                       int* __restrict__ cur_s,
                       const int* __restrict__ cnt_o, int* __restrict__ offs_o,
                       int* __restrict__ cur_o, int n) {
    const int* in = blockIdx.x ? cnt_o : cnt_s;
    int* out = blockIdx.x ? offs_o : offs_s;
    int* cur = blockIdx.x ? cur_o : cur_s;
    __shared__ int wsum[16];
    __shared__ int carrysh;
    int lane = threadIdx.x & 63, wid = threadIdx.x >> 6;
    if (threadIdx.x == 0) carrysh = 0;
    __syncthreads();
    for (int base = 0; base < n; base += 1024) {
        int i = base + threadIdx.x;
        int v = (i < n) ? in[i] : 0;
        int x = v;
        #pragma unroll
        for (int d = 1; d < 64; d <<= 1) {
            int u = __shfl_up(x, d, 64);
            if (lane >= d) x += u;
        }
        if (lane == 63) wsum[wid] = x;
        __syncthreads();
        if (wid == 0 && lane < 16) {
            int w = wsum[lane];
            int y = w;
            #pragma unroll
            for (int d = 1; d < 16; d <<= 1) {
                int u = __shfl_up(y, d, 16);
                if (lane >= d) y += u;
            }
            wsum[lane] = y - w;
        }
        __syncthreads();
        int excl = carrysh + wsum[wid] + x - v;
        if (i < n) { out[i] = excl; cur[i] = excl; }
        __syncthreads();
        if (threadIdx.x == 1023) carrysh += wsum[15] + x;
        __syncthreads();
    }
}

__global__ void k_scatter(const int* __restrict__ s_u, const int* __restrict__ o_u,
                          int* __restrict__ cur_s, int* __restrict__ cur_o,
                          int* __restrict__ bkt_s, int* __restrict__ bkt_o, int nt) {
    int t = blockIdx.x * blockDim.x + threadIdx.x;
    if (t < nt) {
        bkt_s[atomicAdd(&cur_s[s_u[t]], 1)] = t;
        bkt_o[atomicAdd(&cur_o[o_u[t]], 1)] = t;
    }
}

// ---------------------------------------------------------------------------
// Stage 3: per-node latent sums. blockIdx.y = 0 -> rowsum (s buckets),
//          blockIdx.y = 1 -> colsum (o buckets). One dispatch.
__global__ void k_latsum(const float* __restrict__ latents,
                         const int* __restrict__ bkt_s,
                         const int* __restrict__ offs_s,
                         const int* __restrict__ cnt_s,
                         float* __restrict__ rowsum,
                         const int* __restrict__ bkt_o,
                         const int* __restrict__ offs_o,
                         const int* __restrict__ cnt_o,
                         float* __restrict__ colsum, int n) {
    const int* bkt  = blockIdx.y ? bkt_o : bkt_s;
    const int* offs = blockIdx.y ? offs_o : offs_s;
    const int* cnt  = blockIdx.y ? cnt_o : cnt_s;
    float* dst      = blockIdx.y ? colsum : rowsum;
    __shared__ float r0s;
    if (threadIdx.x == 0) r0s = 0.f;
    __syncthreads();
    int i = blockIdx.x * blockDim.x + threadIdx.x;
    int v = i >> 4, k = i & 15;
    float ls = 0.f;
    if (v < n) {
        int beg = offs[v], d = cnt[v];
        for (int j = 0; j < d; ++j) {
            int t = bkt[beg + j];
            ls += latents[t * RP + k];
        }
        if (k >= 1 && ls != 0.f) atomicAdd(&dst[v * k], ls);
        if (k == 0 && ls != 0.f) atomicAdd(&r0s, ls);
    }
    __syncthreads();
    if (threadIdx.x == 0 && r0s != 0.f) atomicAdd(&dst[0], r0s);
}

// ---------------------------------------------------------------------------
// Stage 4: per-o accumulation into raw h (no bias/relu yet).
__global__ void k_h_acc(const float* __restrict__ latents,
                        const int* __restrict__ bkt_o,
                        const int* __restrict__ offs_o,
                        const int* __restrict__ cnt_o,
                        const int* __restrict__ s_u,
                        const float* __restrict__ colsum,
                        const float* __restrict__ w1,
                        float* __restrict__ h, int n) {
    int i = blockIdx.x * blockDim.x + threadIdx.x;
    int o = i >> 4, k = i & 15;
    if (o >= n) return;
    int d = cnt_o[o];
    if (d == 0) return;
    int beg = offs_o[o];
    float W[RP];
    #pragma unroll
    for (int r = 0; r < RP; ++r)
        W[r] = w1[(size_t)(o * r) * EMB + k];
    float rcp_cs = 1.f / colsum[o * k];
    for (int j = 0; j < d; ++j) {
        int t = bkt_o[beg + j];
        float ln = latents[t * RP + k] * rcp_cs;
        float acc = 0.f;
        #pragma unroll
        for (int r = 0; r < RP; ++r)
            acc += __shfl(ln, r, 16) * W[r];
        atomicAdd(&h[s_u[t] * EMB + k], acc);
    }
}

// ---------------------------------------------------------------------------
// Stage 5+6: per-s outer-product; h read applies bias+relu on the fly.
__global__ void k_h2(const float* __restrict__ latents,
                     const int* __restrict__ bkt_s,
                     const int* __restrict__ offs_s,
                     const int* __restrict__ cnt_s,
                     const int* __restrict__ o_u,
                     const float* __restrict__ rowsum,
                     const float* __restrict__ h,
                     const float* __restrict__ bias1,
                     float* __restrict__ h2, int n) {
    __shared__ float r0acc[EMB];
    if (threadIdx.x < EMB) r0acc[threadIdx.x] = 0.f;
    __syncthreads();
    int i = blockIdx.x * blockDim.x + threadIdx.x;
    int s = i >> 4, k = i & 15;
    float b1k = bias1[k];
    float M[RP];
    #pragma unroll
    for (int r = 0; r < RP; ++r) M[r] = 0.f;
    int d = 0;
    if (s < n) {
        int beg = offs_s[s];
        d = cnt_s[s];
        for (int j = 0; j < d; ++j) {
            int t = bkt_s[beg + j];
            int o = o_u[t];
            float hv = fmaxf(h[o * EMB + k] + b1k, 0.f);
            float lat = latents[t * RP + k];
            #pragma unroll
            for (int r = 0; r < RP; ++r)
                M[r] += __shfl(lat, r, 16) * hv;
        }
    }
    if (s < n && d > 0) {
        float rs = rowsum[s * k];
        float rs0 = __shfl(rs, 0, 16);
        atomicAdd(&r0acc[k], M[0] / rs0);
        #pragma unroll
        for (int r = 1; r < RP; ++r) {
            float rsr = __shfl(rs, r, 16);
            atomicAdd(&h2[(size_t)(s * r) * EMB + k], M[r] / rsr);
        }
    }
    __syncthreads();
    if (threadIdx.x < EMB) {
        float v = r0acc[threadIdx.x];
        if (v != 0.f) atomicAdd(&h2[threadIdx.x], v);
    }
}

// ---------------------------------------------------------------------------
// Stage 7: w2 staged in LDS (40 KB); thread = (node, 20-col half);
// all w2 reads are float4 LDS broadcasts; float4 out stores.
#define CB2 20
__global__ void k_out(const float* __restrict__ w2,
                      const float* __restrict__ bias2,
                      const float* __restrict__ h2,
                      float* __restrict__ out, int n) {
    __shared__ float w2s[RP * EMB * NC];          // 10240 floats = 40 KB
    for (int i = threadIdx.x; i < RP * EMB * NC; i += 256)
        w2s[i] = w2[i];
    __syncthreads();
    int gi = blockIdx.x * blockDim.x + threadIdx.x;
    int node = gi >> 1;
    int c0 = (gi & 1) * CB2;
    if (node >= n) return;
    float acc[CB2];
    #pragma unroll
    for (int c = 0; c < CB2; ++c) acc[c] = bias2[c0 + c];
    for (int rq = 0; rq < RP; ++rq) {
        const float4* h2row = (const float4*)&h2[((size_t)rq * n + node) * EMB];
        float4 hv4[4];
        #pragma unroll
        for (int q = 0; q < 4; ++q) hv4[q] = h2row[q];
        const float* hv = (const float*)hv4;
        #pragma unroll
        for (int hh = 0; hh < EMB; ++hh) {
            const float4* wrow = (const float4*)&w2s[(rq * EMB + hh) * NC + c0];
            float hvv = hv[hh];
            #pragma unroll
            for (int q5 = 0; q5 < 5; ++q5) {
                float4 wv = wrow[q5];
                acc[q5 * 4 + 0] += wv.x * hvv;
                acc[q5 * 4 + 1] += wv.y * hvv;
                acc[q5 * 4 + 2] += wv.z * hvv;
                acc[q5 * 4 + 3] += wv.w * hvv;
            }
        }
    }
    float4* op = (float4*)&out[node * NC + c0];
    #pragma unroll
    for (int q5 = 0; q5 < 5; ++q5)
        op[q5] = make_float4(acc[q5 * 4], acc[q5 * 4 + 1],
                             acc[q5 * 4 + 2], acc[q5 * 4 + 3]);
}

// ---------------------------------------------------------------------------
extern "C" void kernel_launch(void* const* d_in, const int* in_sizes, int n_in,
                              void* d_out, int out_size, void* d_ws, size_t ws_size,
                              hipStream_t stream) {
    const float* rel_emb = (const float*)d_in[0];
    const float* w1      = (const float*)d_in[1];
    const float* w2      = (const float*)d_in[2];
    const float* b1      = (const float*)d_in[3];
    const float* b2      = (const float*)d_in[4];
    const int*   rm_rows = (const int*)d_in[5];
    const int*   rm_cols = (const int*)d_in[6];
    const float* rm_vals = (const float*)d_in[7];
    const int*   h_rows  = (const int*)d_in[8];   // [0:nt] = s_u
    const int*   v_cols  = (const int*)d_in[11];  // [0:nt] = o_u

    const int nm = in_sizes[5];
    const int ne = in_sizes[8];
    const int nt = ne / RP;
    const int n  = in_sizes[1] / (RP * EMB);

    char* w = (char*)d_ws;
    float* colsum = (float*)w;  w += (size_t)n * RP * 4;
    float* rowsum = (float*)w;  w += (size_t)n * RP * 4;
    float* h2     = (float*)w;  w += (size_t)n * RP * EMB * 4;
    float* h      = (float*)w;  w += (size_t)n * EMB * 4;
    int* cnt_s    = (int*)w;    w += (size_t)n * 4;
    int* cnt_o    = (int*)w;    w += (size_t)n * 4;
    size_t zero_bytes = (size_t)(w - (char*)d_ws);
    float* latents = (float*)w; w += (size_t)nt * RP * 4;
    int* offs_s    = (int*)w;   w += (size_t)n * 4;
    int* cur_s     = (int*)w;   w += (size_t)n * 4;
    int* offs_o    = (int*)w;   w += (size_t)n * 4;
    int* cur_o     = (int*)w;   w += (size_t)n * 4;
    int* bkt_s     = (int*)w;   w += (size_t)nt * 4;
    int* bkt_o     = (int*)w;   w += (size_t)nt * 4;
    if ((size_t)(w - (char*)d_ws) > ws_size) return;

    hipMemsetAsync(d_ws, 0, zero_bytes, stream);

    const int B = 256;
    k_latents<<<dim3((nm * 16 + B - 1) / B), dim3(B), 0, stream>>>(
        rel_emb, rm_rows, rm_cols, rm_vals, latents, nm);
    k_count<<<dim3((nt + B - 1) / B), dim3(B), 0, stream>>>(
        h_rows, v_cols, cnt_s, cnt_o, nt);
    k_scan<<<dim3(2), dim3(1024), 0, stream>>>(
        cnt_s, offs_s, cur_s, cnt_o, offs_o, cur_o, n);
    k_scatter<<<dim3((nt + B - 1) / B), dim3(B), 0, stream>>>(
        h_rows, v_cols, cur_s, cur_o, bkt_s, bkt_o, nt);
    k_latsum<<<dim3((n * 16 + B - 1) / B, 2), dim3(B), 0, stream>>>(
        latents, bkt_s, offs_s, cnt_s, rowsum, bkt_o, offs_o, cnt_o, colsum, n);
    k_h_acc<<<dim3((n * 16 + B - 1) / B), dim3(B), 0, stream>>>(
        latents, bkt_o, offs_o, cnt_o, h_rows, colsum, w1, h, n);
    k_h2<<<dim3((n * 16 + B - 1) / B), dim3(B), 0, stream>>>(
        latents, bkt_s, offs_s, cnt_s, v_cols, rowsum, h, b1, h2, n);
    k_out<<<dim3((n * 2 + B - 1) / B), dim3(B), 0, stream>>>(
        w2, b2, h2, (float*)d_out, n);
}

// Round 5
// 362.612 us; speedup vs baseline: 5.5246x; 1.1416x over previous
//
#include <hip/hip_runtime.h>

#define RP 16
#define EMB 16
#define NC 40

// ---------------------------------------------------------------------------
// Stage 1+2: latents[t,:] = segment-sum over sorted rm_rows, then softmax.
__global__ void k_latents(const float* __restrict__ rel_emb,
                          const int* __restrict__ rows,
                          const int* __restrict__ cols,
                          const float* __restrict__ vals,
                          float* __restrict__ latents, int nm) {
    int i = blockIdx.x * blockDim.x + threadIdx.x;
    int e = i >> 4, k = i & 15;
    if (e >= nm) return;
    int row = rows[e];
    if (e > 0 && rows[e - 1] == row) return;          // not a row leader
    float acc = vals[e] * rel_emb[cols[e] * RP + k];
    while (e + 1 < nm && rows[e + 1] == row) {
        ++e;
        acc += vals[e] * rel_emb[cols[e] * RP + k];
    }
    float m = acc;
    #pragma unroll
    for (int d = 1; d < 16; d <<= 1) m = fmaxf(m, __shfl_xor(m, d, 16));
    float v = expf(acc - m);
    float s = v;
    #pragma unroll
    for (int d = 1; d < 16; d <<= 1) s += __shfl_xor(s, d, 16);
    latents[row * RP + k] = v / s;
}

// ---------------------------------------------------------------------------
// r0 totals: rowsum[0] += sum_t latents[t,0]; colsum[0] likewise.
// (The r=0 slice maps every t to flat index 0 in both index spaces.)
__global__ void k_r0(const float* __restrict__ latents,
                     float* __restrict__ rowsum, float* __restrict__ colsum,
                     int nt) {
    float acc = 0.f;
    for (int t = blockIdx.x * blockDim.x + threadIdx.x; t < nt;
         t += gridDim.x * blockDim.x)
        acc += latents[t * RP];
    #pragma unroll
    for (int d = 32; d; d >>= 1) acc += __shfl_down(acc, d, 64);
    __shared__ float sm[4];
    int lane = threadIdx.x & 63, wid = threadIdx.x >> 6;
    if (lane == 0) sm[wid] = acc;
    __syncthreads();
    if (threadIdx.x == 0) {
        float tot = sm[0] + sm[1] + sm[2] + sm[3];
        atomicAdd(&rowsum[0], tot);
        atomicAdd(&colsum[0], tot);
    }
}

// ---------------------------------------------------------------------------
// Bucket build.
__global__ void k_count(const int* __restrict__ s_u, const int* __restrict__ o_u,
                        int* __restrict__ cnt_s, int* __restrict__ cnt_o, int nt) {
    int t = blockIdx.x * blockDim.x + threadIdx.x;
    if (t < nt) {
        atomicAdd(&cnt_s[s_u[t]], 1);
        atomicAdd(&cnt_o[o_u[t]], 1);
    }
}

__global__ void k_scan(const int* __restrict__ cnt_s, int* __restrict__ offs_s,
                       int* __restrict__ cur_s,
                       const int* __restrict__ cnt_o, int* __restrict__ offs_o,
                       int* __restrict__ cur_o, int n) {
    const int* in = blockIdx.x ? cnt_o : cnt_s;
    int* out = blockIdx.x ? offs_o : offs_s;
    int* cur = blockIdx.x ? cur_o : cur_s;
    __shared__ int wsum[16];
    __shared__ int carrysh;
    int lane = threadIdx.x & 63, wid = threadIdx.x >> 6;
    if (threadIdx.x == 0) carrysh = 0;
    __syncthreads();
    for (int base = 0; base < n; base += 1024) {
        int i = base + threadIdx.x;
        int v = (i < n) ? in[i] : 0;
        int x = v;
        #pragma unroll
        for (int d = 1; d < 64; d <<= 1) {
            int u = __shfl_up(x, d, 64);
            if (lane >= d) x += u;
        }
        if (lane == 63) wsum[wid] = x;
        __syncthreads();
        if (wid == 0 && lane < 16) {
            int w = wsum[lane];
            int y = w;
            #pragma unroll
            for (int d = 1; d < 16; d <<= 1) {
                int u = __shfl_up(y, d, 16);
                if (lane >= d) y += u;
            }
            wsum[lane] = y - w;
        }
        __syncthreads();
        int excl = carrysh + wsum[wid] + x - v;
        if (i < n) { out[i] = excl; cur[i] = excl; }
        __syncthreads();
        if (threadIdx.x == 1023) carrysh += wsum[15] + x;
        __syncthreads();
    }
}

__global__ void k_scatter(const int* __restrict__ s_u, const int* __restrict__ o_u,
                          int* __restrict__ cur_s, int* __restrict__ cur_o,
                          int* __restrict__ bkt_s, int* __restrict__ bkt_o, int nt) {
    int t = blockIdx.x * blockDim.x + threadIdx.x;
    if (t < nt) {
        bkt_s[atomicAdd(&cur_s[s_u[t]], 1)] = t;
        bkt_o[atomicAdd(&cur_o[o_u[t]], 1)] = t;
    }
}

// ---------------------------------------------------------------------------
// Stage 3: per-node latent sums. blockIdx.y = 0 -> rowsum, 1 -> colsum.
// k=0 lane's total handled globally by k_r0; only k>=1 atomics here.
// 16-entry chunks: parallel bkt loads, entries broadcast by shfl.
__global__ void k_latsum(const float* __restrict__ latents,
                         const int* __restrict__ bkt_s,
                         const int* __restrict__ offs_s,
                         const int* __restrict__ cnt_s,
                         float* __restrict__ rowsum,
                         const int* __restrict__ bkt_o,
                         const int* __restrict__ offs_o,
                         const int* __restrict__ cnt_o,
                         float* __restrict__ colsum, int n) {
    const int* bkt  = blockIdx.y ? bkt_o : bkt_s;
    const int* offs = blockIdx.y ? offs_o : offs_s;
    const int* cnt  = blockIdx.y ? cnt_o : cnt_s;
    float* dst      = blockIdx.y ? colsum : rowsum;
    int i = blockIdx.x * blockDim.x + threadIdx.x;
    int v = i >> 4, k = i & 15;
    if (v >= n) return;
    int beg = offs[v], d = cnt[v];
    if (d == 0) return;
    float ls = 0.f;
    for (int j0 = 0; j0 < d; j0 += 16) {
        int tj = bkt[beg + min(j0 + k, d - 1)];
        #pragma unroll
        for (int e = 0; e < 16; ++e) {
            if (j0 + e >= d) break;                   // uniform across group
            int t = __shfl(tj, e, 16);
            ls += latents[t * RP + k];
        }
    }
    if (k >= 1) atomicAdd(&dst[v * k], ls);
}

// ---------------------------------------------------------------------------
// Stage 4: per-o accumulation into raw h (no bias/relu yet). Chunked gathers.
__global__ void k_h_acc(const float* __restrict__ latents,
                        const int* __restrict__ bkt_o,
                        const int* __restrict__ offs_o,
                        const int* __restrict__ cnt_o,
                        const int* __restrict__ s_u,
                        const float* __restrict__ colsum,
                        const float* __restrict__ w1,
                        float* __restrict__ h, int n) {
    int i = blockIdx.x * blockDim.x + threadIdx.x;
    int o = i >> 4, k = i & 15;
    if (o >= n) return;
    int d = cnt_o[o];
    if (d == 0) return;
    int beg = offs_o[o];
    float W[RP];
    #pragma unroll
    for (int r = 0; r < RP; ++r)
        W[r] = w1[(size_t)(o * r) * EMB + k];
    float rcp_cs = 1.f / colsum[o * k];
    for (int j0 = 0; j0 < d; j0 += 16) {
        int tj = bkt_o[beg + min(j0 + k, d - 1)];
        int sj = s_u[tj];
        #pragma unroll
        for (int e = 0; e < 16; ++e) {
            if (j0 + e >= d) break;                   // uniform
            int t = __shfl(tj, e, 16);
            float ln = latents[t * RP + k] * rcp_cs;
            float acc = 0.f;
            #pragma unroll
            for (int r = 0; r < RP; ++r)
                acc += __shfl(ln, r, 16) * W[r];
            int s = __shfl(sj, e, 16);
            atomicAdd(&h[s * EMB + k], acc);
        }
    }
}

// ---------------------------------------------------------------------------
// Stage 5+6: per-s outer-product; h read applies bias+relu on the fly.
// r==0 contributions -> per-block partials in r0part (no hot-line atomics).
__global__ void k_h2(const float* __restrict__ latents,
                     const int* __restrict__ bkt_s,
                     const int* __restrict__ offs_s,
                     const int* __restrict__ cnt_s,
                     const int* __restrict__ o_u,
                     const float* __restrict__ rowsum,
                     const float* __restrict__ h,
                     const float* __restrict__ bias1,
                     float* __restrict__ h2,
                     float* __restrict__ r0part, int n) {
    __shared__ float r0acc[EMB];
    if (threadIdx.x < EMB) r0acc[threadIdx.x] = 0.f;
    __syncthreads();
    int i = blockIdx.x * blockDim.x + threadIdx.x;
    int s = i >> 4, k = i & 15;
    float b1k = bias1[k];
    float M[RP];
    #pragma unroll
    for (int r = 0; r < RP; ++r) M[r] = 0.f;
    int d = 0;
    if (s < n) {
        int beg = offs_s[s];
        d = cnt_s[s];
        for (int j0 = 0; j0 < d; j0 += 16) {
            int tj = bkt_s[beg + min(j0 + k, d - 1)];
            int oj = o_u[tj];
            #pragma unroll
            for (int e = 0; e < 16; ++e) {
                if (j0 + e >= d) break;               // uniform
                int t = __shfl(tj, e, 16);
                int o = __shfl(oj, e, 16);
                float hv = fmaxf(h[o * EMB + k] + b1k, 0.f);
                float lat = latents[t * RP + k];
                #pragma unroll
                for (int r = 0; r < RP; ++r)
                    M[r] += __shfl(lat, r, 16) * hv;
            }
        }
    }
    if (s < n && d > 0) {
        float rs = rowsum[s * k];
        float rs0 = __shfl(rs, 0, 16);
        atomicAdd(&r0acc[k], M[0] / rs0);
        #pragma unroll
        for (int r = 1; r < RP; ++r) {
            float rsr = __shfl(rs, r, 16);
            atomicAdd(&h2[(size_t)(s * r) * EMB + k], M[r] / rsr);
        }
    }
    __syncthreads();
    if (threadIdx.x < EMB)
        r0part[(size_t)blockIdx.x * EMB + threadIdx.x] = r0acc[threadIdx.x];
}

// Reduce r0part (nblk x 16) into h2[0:16]. One block of 1024.
__global__ void k_h2r0(const float* __restrict__ r0part,
                       float* __restrict__ h2, int nblk) {
    __shared__ float red[1024];
    int k = threadIdx.x & 15, j0 = threadIdx.x >> 4;   // j0 in [0,64)
    float acc = 0.f;
    for (int j = j0; j < nblk; j += 64)
        acc += r0part[(size_t)j * EMB + k];
    red[j0 * 16 + k] = acc;
    __syncthreads();
    #pragma unroll
    for (int st = 32; st >= 1; st >>= 1) {
        if (j0 < st) red[j0 * 16 + k] += red[(j0 + st) * 16 + k];
        __syncthreads();
    }
    if (threadIdx.x < 16) h2[threadIdx.x] += red[threadIdx.x];
}

// ---------------------------------------------------------------------------
// Stage 7: w2 staged in LDS (40 KB); thread = (node, 20-col half).
#define CB2 20
__global__ void k_out(const float* __restrict__ w2,
                      const float* __restrict__ bias2,
                      const float* __restrict__ h2,
                      float* __restrict__ out, int n) {
    __shared__ float w2s[RP * EMB * NC];          // 10240 floats = 40 KB
    for (int i = threadIdx.x; i < RP * EMB * NC; i += 256)
        w2s[i] = w2[i];
    __syncthreads();
    int gi = blockIdx.x * blockDim.x + threadIdx.x;
    int node = gi >> 1;
    int c0 = (gi & 1) * CB2;
    if (node >= n) return;
    float acc[CB2];
    #pragma unroll
    for (int c = 0; c < CB2; ++c) acc[c] = bias2[c0 + c];
    for (int rq = 0; rq < RP; ++rq) {
        const float4* h2row = (const float4*)&h2[((size_t)rq * n + node) * EMB];
        float4 hv4[4];
        #pragma unroll
        for (int q = 0; q < 4; ++q) hv4[q] = h2row[q];
        const float* hv = (const float*)hv4;
        #pragma unroll
        for (int hh = 0; hh < EMB; ++hh) {
            const float4* wrow = (const float4*)&w2s[(rq * EMB + hh) * NC + c0];
            float hvv = hv[hh];
            #pragma unroll
            for (int q5 = 0; q5 < 5; ++q5) {
                float4 wv = wrow[q5];
                acc[q5 * 4 + 0] += wv.x * hvv;
                acc[q5 * 4 + 1] += wv.y * hvv;
                acc[q5 * 4 + 2] += wv.z * hvv;
                acc[q5 * 4 + 3] += wv.w * hvv;
            }
        }
    }
    float4* op = (float4*)&out[node * NC + c0];
    #pragma unroll
    for (int q5 = 0; q5 < 5; ++q5)
        op[q5] = make_float4(acc[q5 * 4], acc[q5 * 4 + 1],
                             acc[q5 * 4 + 2], acc[q5 * 4 + 3]);
}

// ---------------------------------------------------------------------------
extern "C" void kernel_launch(void* const* d_in, const int* in_sizes, int n_in,
                              void* d_out, int out_size, void* d_ws, size_t ws_size,
                              hipStream_t stream) {
    const float* rel_emb = (const float*)d_in[0];
    const float* w1      = (const float*)d_in[1];
    const float* w2      = (const float*)d_in[2];
    const float* b1      = (const float*)d_in[3];
    const float* b2      = (const float*)d_in[4];
    const int*   rm_rows = (const int*)d_in[5];
    const int*   rm_cols = (const int*)d_in[6];
    const float* rm_vals = (const float*)d_in[7];
    const int*   h_rows  = (const int*)d_in[8];   // [0:nt] = s_u
    const int*   v_cols  = (const int*)d_in[11];  // [0:nt] = o_u

    const int nm = in_sizes[5];
    const int ne = in_sizes[8];
    const int nt = ne / RP;
    const int n  = in_sizes[1] / (RP * EMB);

    const int B = 256;
    const int nblk_h2 = (n * 16 + B - 1) / B;

    char* w = (char*)d_ws;
    float* colsum = (float*)w;  w += (size_t)n * RP * 4;
    float* rowsum = (float*)w;  w += (size_t)n * RP * 4;
    float* h2     = (float*)w;  w += (size_t)n * RP * EMB * 4;
    float* h      = (float*)w;  w += (size_t)n * EMB * 4;
    int* cnt_s    = (int*)w;    w += (size_t)n * 4;
    int* cnt_o    = (int*)w;    w += (size_t)n * 4;
    size_t zero_bytes = (size_t)(w - (char*)d_ws);
    float* latents = (float*)w; w += (size_t)nt * RP * 4;
    int* offs_s    = (int*)w;   w += (size_t)n * 4;
    int* cur_s     = (int*)w;   w += (size_t)n * 4;
    int* offs_o    = (int*)w;   w += (size_t)n * 4;
    int* cur_o     = (int*)w;   w += (size_t)n * 4;
    int* bkt_s     = (int*)w;   w += (size_t)nt * 4;
    int* bkt_o     = (int*)w;   w += (size_t)nt * 4;
    float* r0part  = (float*)w; w += (size_t)nblk_h2 * EMB * 4;
    if ((size_t)(w - (char*)d_ws) > ws_size) return;

    hipMemsetAsync(d_ws, 0, zero_bytes, stream);

    k_latents<<<dim3((nm * 16 + B - 1) / B), dim3(B), 0, stream>>>(
        rel_emb, rm_rows, rm_cols, rm_vals, latents, nm);
    k_r0<<<dim3(64), dim3(B), 0, stream>>>(latents, rowsum, colsum, nt);
    k_count<<<dim3((nt + B - 1) / B), dim3(B), 0, stream>>>(
        h_rows, v_cols, cnt_s, cnt_o, nt);
    k_scan<<<dim3(2), dim3(1024), 0, stream>>>(
        cnt_s, offs_s, cur_s, cnt_o, offs_o, cur_o, n);
    k_scatter<<<dim3((nt + B - 1) / B), dim3(B), 0, stream>>>(
        h_rows, v_cols, cur_s, cur_o, bkt_s, bkt_o, nt);
    k_latsum<<<dim3((n * 16 + B - 1) / B, 2), dim3(B), 0, stream>>>(
        latents, bkt_s, offs_s, cnt_s, rowsum, bkt_o, offs_o, cnt_o, colsum, n);
    k_h_acc<<<dim3((n * 16 + B - 1) / B), dim3(B), 0, stream>>>(
        latents, bkt_o, offs_o, cnt_o, h_rows, colsum, w1, h, n);
    k_h2<<<dim3(nblk_h2), dim3(B), 0, stream>>>(
        latents, bkt_s, offs_s, cnt_s, v_cols, rowsum, h, b1, h2, r0part, n);
    k_h2r0<<<dim3(1), dim3(1024), 0, stream>>>(r0part, h2, nblk_h2);
    k_out<<<dim3((n * 2 + B - 1) / B), dim3(B), 0, stream>>>(
        w2, b2, h2, (float*)d_out, n);
}

// Round 6
// 319.938 us; speedup vs baseline: 6.2615x; 1.1334x over previous
//
#include <hip/hip_runtime.h>

#define RP 16
#define EMB 16
#define NC 40

// ---------------------------------------------------------------------------
// Stage 1+2: latents[t,:] = segment-sum over sorted rm_rows, then softmax.
__global__ void k_latents(const float* __restrict__ rel_emb,
                          const int* __restrict__ rows,
                          const int* __restrict__ cols,
                          const float* __restrict__ vals,
                          float* __restrict__ latents, int nm) {
    int i = blockIdx.x * blockDim.x + threadIdx.x;
    int e = i >> 4, k = i & 15;
    if (e >= nm) return;
    int row = rows[e];
    if (e > 0 && rows[e - 1] == row) return;          // not a row leader
    float acc = vals[e] * rel_emb[cols[e] * RP + k];
    while (e + 1 < nm && rows[e + 1] == row) {
        ++e;
        acc += vals[e] * rel_emb[cols[e] * RP + k];
    }
    float m = acc;
    #pragma unroll
    for (int d = 1; d < 16; d <<= 1) m = fmaxf(m, __shfl_xor(m, d, 16));
    float v = expf(acc - m);
    float s = v;
    #pragma unroll
    for (int d = 1; d < 16; d <<= 1) s += __shfl_xor(s, d, 16);
    latents[row * RP + k] = v / s;
}

// ---------------------------------------------------------------------------
// r0 totals: rowsum[0] += sum_t latents[t,0]; colsum[0] likewise.
__global__ void k_r0(const float* __restrict__ latents,
                     float* __restrict__ rowsum, float* __restrict__ colsum,
                     int nt) {
    float acc = 0.f;
    for (int t = blockIdx.x * blockDim.x + threadIdx.x; t < nt;
         t += gridDim.x * blockDim.x)
        acc += latents[t * RP];
    #pragma unroll
    for (int d = 32; d; d >>= 1) acc += __shfl_down(acc, d, 64);
    __shared__ float sm[4];
    int lane = threadIdx.x & 63, wid = threadIdx.x >> 6;
    if (lane == 0) sm[wid] = acc;
    __syncthreads();
    if (threadIdx.x == 0) {
        float tot = sm[0] + sm[1] + sm[2] + sm[3];
        atomicAdd(&rowsum[0], tot);
        atomicAdd(&colsum[0], tot);
    }
}

// ---------------------------------------------------------------------------
// Bucket build.
__global__ void k_count(const int* __restrict__ s_u, const int* __restrict__ o_u,
                        int* __restrict__ cnt_s, int* __restrict__ cnt_o, int nt) {
    int t = blockIdx.x * blockDim.x + threadIdx.x;
    if (t < nt) {
        atomicAdd(&cnt_s[s_u[t]], 1);
        atomicAdd(&cnt_o[o_u[t]], 1);
    }
}

// ---------------------------------------------------------------------------
// 3-phase hierarchical exclusive scan (n up to 64*1024 per array, 2 arrays).
// Phase 1: per-block local exclusive scan of 1024 elements; block total out.
__global__ void k_scan_blk(const int* __restrict__ cnt_s, int* __restrict__ offs_s,
                           const int* __restrict__ cnt_o, int* __restrict__ offs_o,
                           int* __restrict__ partials, int n, int nblk) {
    const int* in = blockIdx.y ? cnt_o : cnt_s;
    int* out = blockIdx.y ? offs_o : offs_s;
    int tid = threadIdx.x;
    int i0 = blockIdx.x * 1024 + tid * 4;
    int v[4];
    #pragma unroll
    for (int q = 0; q < 4; ++q) {
        int i = i0 + q;
        v[q] = (i < n) ? in[i] : 0;
    }
    int tsum = v[0] + v[1] + v[2] + v[3];
    int lane = tid & 63, wid = tid >> 6;
    int x = tsum;
    #pragma unroll
    for (int d = 1; d < 64; d <<= 1) {
        int u = __shfl_up(x, d, 64);
        if (lane >= d) x += u;
    }
    __shared__ int wsum[4];
    if (lane == 63) wsum[wid] = x;
    __syncthreads();
    int woff = 0;
    for (int wq = 0; wq < wid; ++wq) woff += wsum[wq];
    int run = woff + x - tsum;                       // thread-exclusive prefix
    #pragma unroll
    for (int q = 0; q < 4; ++q) {
        int i = i0 + q;
        if (i < n) out[i] = run;
        run += v[q];
    }
    if (tid == 255) partials[blockIdx.y * nblk + blockIdx.x] = run;  // block total
}

// Phase 2: exclusive scan of block totals; wave 0 -> array s, wave 1 -> array o.
__global__ void k_scan_top(int* __restrict__ partials, int nblk) {
    int w = threadIdx.x >> 6;
    int lane = threadIdx.x & 63;
    int carry = 0;
    for (int base = 0; base < nblk; base += 64) {
        int idx = base + lane;
        int v = (idx < nblk) ? partials[w * nblk + idx] : 0;
        int x = v;
        #pragma unroll
        for (int d = 1; d < 64; d <<= 1) {
            int u = __shfl_up(x, d, 64);
            if (lane >= d) x += u;
        }
        if (idx < nblk) partials[w * nblk + idx] = carry + x - v;
        carry += __shfl(x, 63, 64);
    }
}

// Phase 3: add block offsets; also populate scatter cursors.
__global__ void k_scan_add(int* __restrict__ offs_s, int* __restrict__ cur_s,
                           int* __restrict__ offs_o, int* __restrict__ cur_o,
                           const int* __restrict__ partials, int n, int nblk) {
    int* out = blockIdx.y ? offs_o : offs_s;
    int* cur = blockIdx.y ? cur_o : cur_s;
    int add = partials[blockIdx.y * nblk + blockIdx.x];
    int i0 = blockIdx.x * 1024 + threadIdx.x * 4;
    #pragma unroll
    for (int q = 0; q < 4; ++q) {
        int i = i0 + q;
        if (i < n) {
            int vv = out[i] + add;
            out[i] = vv;
            cur[i] = vv;
        }
    }
}

__global__ void k_scatter(const int* __restrict__ s_u, const int* __restrict__ o_u,
                          int* __restrict__ cur_s, int* __restrict__ cur_o,
                          int* __restrict__ bkt_s, int* __restrict__ bkt_o, int nt) {
    int t = blockIdx.x * blockDim.x + threadIdx.x;
    if (t < nt) {
        bkt_s[atomicAdd(&cur_s[s_u[t]], 1)] = t;
        bkt_o[atomicAdd(&cur_o[o_u[t]], 1)] = t;
    }
}

// ---------------------------------------------------------------------------
// Stage 3: per-node latent sums. blockIdx.y = 0 -> rowsum, 1 -> colsum.
__global__ void k_latsum(const float* __restrict__ latents,
                         const int* __restrict__ bkt_s,
                         const int* __restrict__ offs_s,
                         const int* __restrict__ cnt_s,
                         float* __restrict__ rowsum,
                         const int* __restrict__ bkt_o,
                         const int* __restrict__ offs_o,
                         const int* __restrict__ cnt_o,
                         float* __restrict__ colsum, int n) {
    const int* bkt  = blockIdx.y ? bkt_o : bkt_s;
    const int* offs = blockIdx.y ? offs_o : offs_s;
    const int* cnt  = blockIdx.y ? cnt_o : cnt_s;
    float* dst      = blockIdx.y ? colsum : rowsum;
    int i = blockIdx.x * blockDim.x + threadIdx.x;
    int v = i >> 4, k = i & 15;
    if (v >= n) return;
    int beg = offs[v], d = cnt[v];
    if (d == 0) return;
    float ls = 0.f;
    for (int j0 = 0; j0 < d; j0 += 16) {
        int tj = bkt[beg + min(j0 + k, d - 1)];
        #pragma unroll
        for (int e = 0; e < 16; ++e) {
            if (j0 + e >= d) break;                   // uniform across group
            int t = __shfl(tj, e, 16);
            ls += latents[t * RP + k];
        }
    }
    if (k >= 1) atomicAdd(&dst[v * k], ls);
}

// ---------------------------------------------------------------------------
// Stage 4: per-o accumulation into raw h (no bias/relu yet). Chunked gathers.
__global__ void k_h_acc(const float* __restrict__ latents,
                        const int* __restrict__ bkt_o,
                        const int* __restrict__ offs_o,
                        const int* __restrict__ cnt_o,
                        const int* __restrict__ s_u,
                        const float* __restrict__ colsum,
                        const float* __restrict__ w1,
                        float* __restrict__ h, int n) {
    int i = blockIdx.x * blockDim.x + threadIdx.x;
    int o = i >> 4, k = i & 15;
    if (o >= n) return;
    int d = cnt_o[o];
    if (d == 0) return;
    int beg = offs_o[o];
    float W[RP];
    #pragma unroll
    for (int r = 0; r < RP; ++r)
        W[r] = w1[(size_t)(o * r) * EMB + k];
    float rcp_cs = 1.f / colsum[o * k];
    for (int j0 = 0; j0 < d; j0 += 16) {
        int tj = bkt_o[beg + min(j0 + k, d - 1)];
        int sj = s_u[tj];
        #pragma unroll
        for (int e = 0; e < 16; ++e) {
            if (j0 + e >= d) break;                   // uniform
            int t = __shfl(tj, e, 16);
            float ln = latents[t * RP + k] * rcp_cs;
            float acc = 0.f;
            #pragma unroll
            for (int r = 0; r < RP; ++r)
                acc += __shfl(ln, r, 16) * W[r];
            int s = __shfl(sj, e, 16);
            atomicAdd(&h[s * EMB + k], acc);
        }
    }
}

// ---------------------------------------------------------------------------
// Stage 5+6: per-s outer-product; h read applies bias+relu on the fly.
__global__ void k_h2(const float* __restrict__ latents,
                     const int* __restrict__ bkt_s,
                     const int* __restrict__ offs_s,
                     const int* __restrict__ cnt_s,
                     const int* __restrict__ o_u,
                     const float* __restrict__ rowsum,
                     const float* __restrict__ h,
                     const float* __restrict__ bias1,
                     float* __restrict__ h2,
                     float* __restrict__ r0part, int n) {
    __shared__ float r0acc[EMB];
    if (threadIdx.x < EMB) r0acc[threadIdx.x] = 0.f;
    __syncthreads();
    int i = blockIdx.x * blockDim.x + threadIdx.x;
    int s = i >> 4, k = i & 15;
    float b1k = bias1[k];
    float M[RP];
    #pragma unroll
    for (int r = 0; r < RP; ++r) M[r] = 0.f;
    int d = 0;
    if (s < n) {
        int beg = offs_s[s];
        d = cnt_s[s];
        for (int j0 = 0; j0 < d; j0 += 16) {
            int tj = bkt_s[beg + min(j0 + k, d - 1)];
            int oj = o_u[tj];
            #pragma unroll
            for (int e = 0; e < 16; ++e) {
                if (j0 + e >= d) break;               // uniform
                int t = __shfl(tj, e, 16);
                int o = __shfl(oj, e, 16);
                float hv = fmaxf(h[o * EMB + k] + b1k, 0.f);
                float lat = latents[t * RP + k];
                #pragma unroll
                for (int r = 0; r < RP; ++r)
                    M[r] += __shfl(lat, r, 16) * hv;
            }
        }
    }
    if (s < n && d > 0) {
        float rs = rowsum[s * k];
        float rs0 = __shfl(rs, 0, 16);
        atomicAdd(&r0acc[k], M[0] / rs0);
        #pragma unroll
        for (int r = 1; r < RP; ++r) {
            float rsr = __shfl(rs, r, 16);
            atomicAdd(&h2[(size_t)(s * r) * EMB + k], M[r] / rsr);
        }
    }
    __syncthreads();
    if (threadIdx.x < EMB)
        r0part[(size_t)blockIdx.x * EMB + threadIdx.x] = r0acc[threadIdx.x];
}

// Reduce r0part (nblk x 16) into h2[0:16]. One block of 1024.
__global__ void k_h2r0(const float* __restrict__ r0part,
                       float* __restrict__ h2, int nblk) {
    __shared__ float red[1024];
    int k = threadIdx.x & 15, j0 = threadIdx.x >> 4;   // j0 in [0,64)
    float acc = 0.f;
    for (int j = j0; j < nblk; j += 64)
        acc += r0part[(size_t)j * EMB + k];
    red[j0 * 16 + k] = acc;
    __syncthreads();
    #pragma unroll
    for (int st = 32; st >= 1; st >>= 1) {
        if (j0 < st) red[j0 * 16 + k] += red[(j0 + st) * 16 + k];
        __syncthreads();
    }
    if (threadIdx.x < 16) h2[threadIdx.x] += red[threadIdx.x];
}

// ---------------------------------------------------------------------------
// Stage 7: w2 staged in LDS (40 KB); thread = (node, 20-col half).
#define CB2 20
__global__ void k_out(const float* __restrict__ w2,
                      const float* __restrict__ bias2,
                      const float* __restrict__ h2,
                      float* __restrict__ out, int n) {
    __shared__ float w2s[RP * EMB * NC];          // 10240 floats = 40 KB
    for (int i = threadIdx.x; i < RP * EMB * NC; i += 256)
        w2s[i] = w2[i];
    __syncthreads();
    int gi = blockIdx.x * blockDim.x + threadIdx.x;
    int node = gi >> 1;
    int c0 = (gi & 1) * CB2;
    if (node >= n) return;
    float acc[CB2];
    #pragma unroll
    for (int c = 0; c < CB2; ++c) acc[c] = bias2[c0 + c];
    for (int rq = 0; rq < RP; ++rq) {
        const float4* h2row = (const float4*)&h2[((size_t)rq * n + node) * EMB];
        float4 hv4[4];
        #pragma unroll
        for (int q = 0; q < 4; ++q) hv4[q] = h2row[q];
        const float* hv = (const float*)hv4;
        #pragma unroll
        for (int hh = 0; hh < EMB; ++hh) {
            const float4* wrow = (const float4*)&w2s[(rq * EMB + hh) * NC + c0];
            float hvv = hv[hh];
            #pragma unroll
            for (int q5 = 0; q5 < 5; ++q5) {
                float4 wv = wrow[q5];
                acc[q5 * 4 + 0] += wv.x * hvv;
                acc[q5 * 4 + 1] += wv.y * hvv;
                acc[q5 * 4 + 2] += wv.z * hvv;
                acc[q5 * 4 + 3] += wv.w * hvv;
            }
        }
    }
    float4* op = (float4*)&out[node * NC + c0];
    #pragma unroll
    for (int q5 = 0; q5 < 5; ++q5)
        op[q5] = make_float4(acc[q5 * 4], acc[q5 * 4 + 1],
                             acc[q5 * 4 + 2], acc[q5 * 4 + 3]);
}

// ---------------------------------------------------------------------------
extern "C" void kernel_launch(void* const* d_in, const int* in_sizes, int n_in,
                              void* d_out, int out_size, void* d_ws, size_t ws_size,
                              hipStream_t stream) {
    const float* rel_emb = (const float*)d_in[0];
    const float* w1      = (const float*)d_in[1];
    const float* w2      = (const float*)d_in[2];
    const float* b1      = (const float*)d_in[3];
    const float* b2      = (const float*)d_in[4];
    const int*   rm_rows = (const int*)d_in[5];
    const int*   rm_cols = (const int*)d_in[6];
    const float* rm_vals = (const float*)d_in[7];
    const int*   h_rows  = (const int*)d_in[8];   // [0:nt] = s_u
    const int*   v_cols  = (const int*)d_in[11];  // [0:nt] = o_u

    const int nm = in_sizes[5];
    const int ne = in_sizes[8];
    const int nt = ne / RP;
    const int n  = in_sizes[1] / (RP * EMB);

    const int B = 256;
    const int nblk_h2 = (n * 16 + B - 1) / B;
    const int nblk_sc = (n + 1023) / 1024;

    char* w = (char*)d_ws;
    float* colsum = (float*)w;  w += (size_t)n * RP * 4;
    float* rowsum = (float*)w;  w += (size_t)n * RP * 4;
    float* h2     = (float*)w;  w += (size_t)n * RP * EMB * 4;
    float* h      = (float*)w;  w += (size_t)n * EMB * 4;
    int* cnt_s    = (int*)w;    w += (size_t)n * 4;
    int* cnt_o    = (int*)w;    w += (size_t)n * 4;
    size_t zero_bytes = (size_t)(w - (char*)d_ws);
    float* latents = (float*)w; w += (size_t)nt * RP * 4;
    int* offs_s    = (int*)w;   w += (size_t)n * 4;
    int* cur_s     = (int*)w;   w += (size_t)n * 4;
    int* offs_o    = (int*)w;   w += (size_t)n * 4;
    int* cur_o     = (int*)w;   w += (size_t)n * 4;
    int* bkt_s     = (int*)w;   w += (size_t)nt * 4;
    int* bkt_o     = (int*)w;   w += (size_t)nt * 4;
    float* r0part  = (float*)w; w += (size_t)nblk_h2 * EMB * 4;
    int* partials  = (int*)w;   w += (size_t)2 * nblk_sc * 4;
    if ((size_t)(w - (char*)d_ws) > ws_size) return;

    hipMemsetAsync(d_ws, 0, zero_bytes, stream);

    k_latents<<<dim3((nm * 16 + B - 1) / B), dim3(B), 0, stream>>>(
        rel_emb, rm_rows, rm_cols, rm_vals, latents, nm);
    k_r0<<<dim3(64), dim3(B), 0, stream>>>(latents, rowsum, colsum, nt);
    k_count<<<dim3((nt + B - 1) / B), dim3(B), 0, stream>>>(
        h_rows, v_cols, cnt_s, cnt_o, nt);
    k_scan_blk<<<dim3(nblk_sc, 2), dim3(B), 0, stream>>>(
        cnt_s, offs_s, cnt_o, offs_o, partials, n, nblk_sc);
    k_scan_top<<<dim3(1), dim3(128), 0, stream>>>(partials, nblk_sc);
    k_scan_add<<<dim3(nblk_sc, 2), dim3(B), 0, stream>>>(
        offs_s, cur_s, offs_o, cur_o, partials, n, nblk_sc);
    k_scatter<<<dim3((nt + B - 1) / B), dim3(B), 0, stream>>>(
        h_rows, v_cols, cur_s, cur_o, bkt_s, bkt_o, nt);
    k_latsum<<<dim3((n * 16 + B - 1) / B, 2), dim3(B), 0, stream>>>(
        latents, bkt_s, offs_s, cnt_s, rowsum, bkt_o, offs_o, cnt_o, colsum, n);
    k_h_acc<<<dim3((n * 16 + B - 1) / B), dim3(B), 0, stream>>>(
        latents, bkt_o, offs_o, cnt_o, h_rows, colsum, w1, h, n);
    k_h2<<<dim3(nblk_h2), dim3(B), 0, stream>>>(
        latents, bkt_s, offs_s, cnt_s, v_cols, rowsum, h, b1, h2, r0part, n);
    k_h2r0<<<dim3(1), dim3(1024), 0, stream>>>(r0part, h2, nblk_h2);
    k_out<<<dim3((n * 2 + B - 1) / B), dim3(B), 0, stream>>>(
        w2, b2, h2, (float*)d_out, n);
}

// Round 7
// 305.230 us; speedup vs baseline: 6.5632x; 1.0482x over previous
//
#include <hip/hip_runtime.h>

#define RP 16
#define EMB 16
#define NC 40

// ---------------------------------------------------------------------------
// Bucket counts per s and per o.
__global__ void k_count(const int* __restrict__ s_u, const int* __restrict__ o_u,
                        int* __restrict__ cnt_s, int* __restrict__ cnt_o, int nt) {
    int t = blockIdx.x * blockDim.x + threadIdx.x;
    if (t < nt) {
        atomicAdd(&cnt_s[s_u[t]], 1);
        atomicAdd(&cnt_o[o_u[t]], 1);
    }
}

// ---------------------------------------------------------------------------
// 3-phase hierarchical exclusive scan (2 arrays via blockIdx.y).
__global__ void k_scan_blk(const int* __restrict__ cnt_s, int* __restrict__ offs_s,
                           const int* __restrict__ cnt_o, int* __restrict__ offs_o,
                           int* __restrict__ partials, int n, int nblk) {
    const int* in = blockIdx.y ? cnt_o : cnt_s;
    int* out = blockIdx.y ? offs_o : offs_s;
    int tid = threadIdx.x;
    int i0 = blockIdx.x * 1024 + tid * 4;
    int v[4];
    #pragma unroll
    for (int q = 0; q < 4; ++q) {
        int i = i0 + q;
        v[q] = (i < n) ? in[i] : 0;
    }
    int tsum = v[0] + v[1] + v[2] + v[3];
    int lane = tid & 63, wid = tid >> 6;
    int x = tsum;
    #pragma unroll
    for (int d = 1; d < 64; d <<= 1) {
        int u = __shfl_up(x, d, 64);
        if (lane >= d) x += u;
    }
    __shared__ int wsum[4];
    if (lane == 63) wsum[wid] = x;
    __syncthreads();
    int woff = 0;
    for (int wq = 0; wq < wid; ++wq) woff += wsum[wq];
    int run = woff + x - tsum;
    #pragma unroll
    for (int q = 0; q < 4; ++q) {
        int i = i0 + q;
        if (i < n) out[i] = run;
        run += v[q];
    }
    if (tid == 255) partials[blockIdx.y * nblk + blockIdx.x] = run;
}

__global__ void k_scan_top(int* __restrict__ partials, int nblk) {
    int w = threadIdx.x >> 6;
    int lane = threadIdx.x & 63;
    int carry = 0;
    for (int base = 0; base < nblk; base += 64) {
        int idx = base + lane;
        int v = (idx < nblk) ? partials[w * nblk + idx] : 0;
        int x = v;
        #pragma unroll
        for (int d = 1; d < 64; d <<= 1) {
            int u = __shfl_up(x, d, 64);
            if (lane >= d) x += u;
        }
        if (idx < nblk) partials[w * nblk + idx] = carry + x - v;
        carry += __shfl(x, 63, 64);
    }
}

__global__ void k_scan_add(int* __restrict__ offs_s, int* __restrict__ cur_s,
                           int* __restrict__ offs_o, int* __restrict__ cur_o,
                           const int* __restrict__ partials, int n, int nblk) {
    int* out = blockIdx.y ? offs_o : offs_s;
    int* cur = blockIdx.y ? cur_o : cur_s;
    int add = partials[blockIdx.y * nblk + blockIdx.x];
    int i0 = blockIdx.x * 1024 + threadIdx.x * 4;
    #pragma unroll
    for (int q = 0; q < 4; ++q) {
        int i = i0 + q;
        if (i < n) {
            int vv = out[i] + add;
            out[i] = vv;
            cur[i] = vv;
        }
    }
}

// ---------------------------------------------------------------------------
// Fused: segment-sum over sorted rm_rows -> softmax -> scatter the row
// directly into bucket order (lat_s for s-buckets, lat_o for o-buckets),
// alongside companion indices ou_s (o per s-entry) / su_o (s per o-entry).
__global__ void k_latents(const float* __restrict__ rel_emb,
                          const int* __restrict__ rows,
                          const int* __restrict__ cols,
                          const float* __restrict__ vals,
                          const int* __restrict__ s_u,
                          const int* __restrict__ o_u,
                          int* __restrict__ cur_s, int* __restrict__ cur_o,
                          float* __restrict__ lat_s, float* __restrict__ lat_o,
                          int* __restrict__ ou_s, int* __restrict__ su_o,
                          int nm) {
    int i = blockIdx.x * blockDim.x + threadIdx.x;
    int e = i >> 4, k = i & 15;
    if (e >= nm) return;
    int row = rows[e];
    if (e > 0 && rows[e - 1] == row) return;          // not a row leader
    float acc = vals[e] * rel_emb[cols[e] * RP + k];
    while (e + 1 < nm && rows[e + 1] == row) {
        ++e;
        acc += vals[e] * rel_emb[cols[e] * RP + k];
    }
    float m = acc;
    #pragma unroll
    for (int d = 1; d < 16; d <<= 1) m = fmaxf(m, __shfl_xor(m, d, 16));
    float v = expf(acc - m);
    float s = v;
    #pragma unroll
    for (int d = 1; d < 16; d <<= 1) s += __shfl_xor(s, d, 16);
    v = v / s;
    int ps = 0, po = 0, su = 0, ou = 0;
    if (k == 0) {
        su = s_u[row];
        ou = o_u[row];
        ps = atomicAdd(&cur_s[su], 1);
        po = atomicAdd(&cur_o[ou], 1);
    }
    ps = __shfl(ps, 0, 16);
    po = __shfl(po, 0, 16);
    lat_s[(size_t)ps * RP + k] = v;
    lat_o[(size_t)po * RP + k] = v;
    if (k == 0) {
        ou_s[ps] = ou;
        su_o[po] = su;
    }
}

// ---------------------------------------------------------------------------
// r0 totals: rowsum[0] += sum_j lat_s[j,0]; colsum[0] likewise (bucket order
// is a permutation of t, so the total is identical).
__global__ void k_r0(const float* __restrict__ lat_s,
                     float* __restrict__ rowsum, float* __restrict__ colsum,
                     int nt) {
    float acc = 0.f;
    for (int t = blockIdx.x * blockDim.x + threadIdx.x; t < nt;
         t += gridDim.x * blockDim.x)
        acc += lat_s[(size_t)t * RP];
    #pragma unroll
    for (int d = 32; d; d >>= 1) acc += __shfl_down(acc, d, 64);
    __shared__ float sm[4];
    int lane = threadIdx.x & 63, wid = threadIdx.x >> 6;
    if (lane == 0) sm[wid] = acc;
    __syncthreads();
    if (threadIdx.x == 0) {
        float tot = sm[0] + sm[1] + sm[2] + sm[3];
        atomicAdd(&rowsum[0], tot);
        atomicAdd(&colsum[0], tot);
    }
}

// ---------------------------------------------------------------------------
// Stage 3: per-node latent sums, linear bucket reads.
// blockIdx.y = 0: lat_s -> rowsum ; 1: lat_o -> colsum.
__global__ void k_latsum(const float* __restrict__ lat_s,
                         const int* __restrict__ offs_s,
                         const int* __restrict__ cnt_s,
                         float* __restrict__ rowsum,
                         const float* __restrict__ lat_o,
                         const int* __restrict__ offs_o,
                         const int* __restrict__ cnt_o,
                         float* __restrict__ colsum, int n) {
    const float* lat = blockIdx.y ? lat_o : lat_s;
    const int* offs = blockIdx.y ? offs_o : offs_s;
    const int* cnt  = blockIdx.y ? cnt_o : cnt_s;
    float* dst      = blockIdx.y ? colsum : rowsum;
    int i = blockIdx.x * blockDim.x + threadIdx.x;
    int v = i >> 4, k = i & 15;
    if (v >= n) return;
    int beg = offs[v], d = cnt[v];
    if (d == 0) return;
    float ls = 0.f;
    int j = 0;
    for (; j + 4 <= d; j += 4) {
        float a0 = lat[(size_t)(beg + j + 0) * RP + k];
        float a1 = lat[(size_t)(beg + j + 1) * RP + k];
        float a2 = lat[(size_t)(beg + j + 2) * RP + k];
        float a3 = lat[(size_t)(beg + j + 3) * RP + k];
        ls += (a0 + a1) + (a2 + a3);
    }
    for (; j < d; ++j) ls += lat[(size_t)(beg + j) * RP + k];
    if (k >= 1) atomicAdd(&dst[v * k], ls);
}

// ---------------------------------------------------------------------------
// Stage 4: per-o accumulation into raw h; linear bucket reads.
__global__ void k_h_acc(const float* __restrict__ lat_o,
                        const int* __restrict__ offs_o,
                        const int* __restrict__ cnt_o,
                        const int* __restrict__ su_o,
                        const float* __restrict__ colsum,
                        const float* __restrict__ w1,
                        float* __restrict__ h, int n) {
    int i = blockIdx.x * blockDim.x + threadIdx.x;
    int o = i >> 4, k = i & 15;
    if (o >= n) return;
    int d = cnt_o[o];
    if (d == 0) return;
    int beg = offs_o[o];
    float W[RP];
    #pragma unroll
    for (int r = 0; r < RP; ++r)
        W[r] = w1[(size_t)(o * r) * EMB + k];
    float rcp_cs = 1.f / colsum[o * k];
    for (int j = 0; j < d; ++j) {
        float ln = lat_o[(size_t)(beg + j) * RP + k] * rcp_cs;
        int s = su_o[beg + j];
        float acc = 0.f;
        #pragma unroll
        for (int r = 0; r < RP; ++r)
            acc += __shfl(ln, r, 16) * W[r];
        atomicAdd(&h[s * EMB + k], acc);
    }
}

// ---------------------------------------------------------------------------
// Stage 5+6: per-s outer-product; linear bucket reads; bias+relu on h read.
__global__ void k_h2(const float* __restrict__ lat_s,
                     const int* __restrict__ offs_s,
                     const int* __restrict__ cnt_s,
                     const int* __restrict__ ou_s,
                     const float* __restrict__ rowsum,
                     const float* __restrict__ h,
                     const float* __restrict__ bias1,
                     float* __restrict__ h2,
                     float* __restrict__ r0part, int n) {
    __shared__ float r0acc[EMB];
    if (threadIdx.x < EMB) r0acc[threadIdx.x] = 0.f;
    __syncthreads();
    int i = blockIdx.x * blockDim.x + threadIdx.x;
    int s = i >> 4, k = i & 15;
    float b1k = bias1[k];
    float M[RP];
    #pragma unroll
    for (int r = 0; r < RP; ++r) M[r] = 0.f;
    int d = 0;
    if (s < n) {
        int beg = offs_s[s];
        d = cnt_s[s];
        for (int j = 0; j < d; ++j) {
            int o = ou_s[beg + j];
            float hv = fmaxf(h[o * EMB + k] + b1k, 0.f);
            float lat = lat_s[(size_t)(beg + j) * RP + k];
            #pragma unroll
            for (int r = 0; r < RP; ++r)
                M[r] += __shfl(lat, r, 16) * hv;
        }
    }
    if (s < n && d > 0) {
        float rs = rowsum[s * k];
        float rs0 = __shfl(rs, 0, 16);
        atomicAdd(&r0acc[k], M[0] / rs0);
        #pragma unroll
        for (int r = 1; r < RP; ++r) {
            float rsr = __shfl(rs, r, 16);
            atomicAdd(&h2[(size_t)(s * r) * EMB + k], M[r] / rsr);
        }
    }
    __syncthreads();
    if (threadIdx.x < EMB)
        r0part[(size_t)blockIdx.x * EMB + threadIdx.x] = r0acc[threadIdx.x];
}

// Reduce r0part (nblk x 16) into h2[0:16]. One block of 1024.
__global__ void k_h2r0(const float* __restrict__ r0part,
                       float* __restrict__ h2, int nblk) {
    __shared__ float red[1024];
    int k = threadIdx.x & 15, j0 = threadIdx.x >> 4;   // j0 in [0,64)
    float acc = 0.f;
    for (int j = j0; j < nblk; j += 64)
        acc += r0part[(size_t)j * EMB + k];
    red[j0 * 16 + k] = acc;
    __syncthreads();
    #pragma unroll
    for (int st = 32; st >= 1; st >>= 1) {
        if (j0 < st) red[j0 * 16 + k] += red[(j0 + st) * 16 + k];
        __syncthreads();
    }
    if (threadIdx.x < 16) h2[threadIdx.x] += red[threadIdx.x];
}

// ---------------------------------------------------------------------------
// Stage 7: w2 staged in LDS (40 KB); thread = (node, 20-col half).
#define CB2 20
__global__ void k_out(const float* __restrict__ w2,
                      const float* __restrict__ bias2,
                      const float* __restrict__ h2,
                      float* __restrict__ out, int n) {
    __shared__ float w2s[RP * EMB * NC];          // 10240 floats = 40 KB
    for (int i = threadIdx.x; i < RP * EMB * NC; i += 256)
        w2s[i] = w2[i];
    __syncthreads();
    int gi = blockIdx.x * blockDim.x + threadIdx.x;
    int node = gi >> 1;
    int c0 = (gi & 1) * CB2;
    if (node >= n) return;
    float acc[CB2];
    #pragma unroll
    for (int c = 0; c < CB2; ++c) acc[c] = bias2[c0 + c];
    for (int rq = 0; rq < RP; ++rq) {
        const float4* h2row = (const float4*)&h2[((size_t)rq * n + node) * EMB];
        float4 hv4[4];
        #pragma unroll
        for (int q = 0; q < 4; ++q) hv4[q] = h2row[q];
        const float* hv = (const float*)hv4;
        #pragma unroll
        for (int hh = 0; hh < EMB; ++hh) {
            const float4* wrow = (const float4*)&w2s[(rq * EMB + hh) * NC + c0];
            float hvv = hv[hh];
            #pragma unroll
            for (int q5 = 0; q5 < 5; ++q5) {
                float4 wv = wrow[q5];
                acc[q5 * 4 + 0] += wv.x * hvv;
                acc[q5 * 4 + 1] += wv.y * hvv;
                acc[q5 * 4 + 2] += wv.z * hvv;
                acc[q5 * 4 + 3] += wv.w * hvv;
            }
        }
    }
    float4* op = (float4*)&out[node * NC + c0];
    #pragma unroll
    for (int q5 = 0; q5 < 5; ++q5)
        op[q5] = make_float4(acc[q5 * 4], acc[q5 * 4 + 1],
                             acc[q5 * 4 + 2], acc[q5 * 4 + 3]);
}

// ---------------------------------------------------------------------------
extern "C" void kernel_launch(void* const* d_in, const int* in_sizes, int n_in,
                              void* d_out, int out_size, void* d_ws, size_t ws_size,
                              hipStream_t stream) {
    const float* rel_emb = (const float*)d_in[0];
    const float* w1      = (const float*)d_in[1];
    const float* w2      = (const float*)d_in[2];
    const float* b1      = (const float*)d_in[3];
    const float* b2      = (const float*)d_in[4];
    const int*   rm_rows = (const int*)d_in[5];
    const int*   rm_cols = (const int*)d_in[6];
    const float* rm_vals = (const float*)d_in[7];
    const int*   h_rows  = (const int*)d_in[8];   // [0:nt] = s_u
    const int*   v_cols  = (const int*)d_in[11];  // [0:nt] = o_u

    const int nm = in_sizes[5];
    const int ne = in_sizes[8];
    const int nt = ne / RP;
    const int n  = in_sizes[1] / (RP * EMB);

    const int B = 256;
    const int nblk_h2 = (n * 16 + B - 1) / B;
    const int nblk_sc = (n + 1023) / 1024;

    char* w = (char*)d_ws;
    float* colsum = (float*)w;  w += (size_t)n * RP * 4;
    float* rowsum = (float*)w;  w += (size_t)n * RP * 4;
    float* h2     = (float*)w;  w += (size_t)n * RP * EMB * 4;
    float* h      = (float*)w;  w += (size_t)n * EMB * 4;
    int* cnt_s    = (int*)w;    w += (size_t)n * 4;
    int* cnt_o    = (int*)w;    w += (size_t)n * 4;
    size_t zero_bytes = (size_t)(w - (char*)d_ws);
    float* lat_s  = (float*)w;  w += (size_t)nt * RP * 4;
    float* lat_o  = (float*)w;  w += (size_t)nt * RP * 4;
    int* ou_s     = (int*)w;    w += (size_t)nt * 4;
    int* su_o     = (int*)w;    w += (size_t)nt * 4;
    int* offs_s   = (int*)w;    w += (size_t)n * 4;
    int* cur_s    = (int*)w;    w += (size_t)n * 4;
    int* offs_o   = (int*)w;    w += (size_t)n * 4;
    int* cur_o    = (int*)w;    w += (size_t)n * 4;
    float* r0part = (float*)w;  w += (size_t)nblk_h2 * EMB * 4;
    int* partials = (int*)w;    w += (size_t)2 * nblk_sc * 4;
    if ((size_t)(w - (char*)d_ws) > ws_size) return;

    hipMemsetAsync(d_ws, 0, zero_bytes, stream);

    k_count<<<dim3((nt + B - 1) / B), dim3(B), 0, stream>>>(
        h_rows, v_cols, cnt_s, cnt_o, nt);
    k_scan_blk<<<dim3(nblk_sc, 2), dim3(B), 0, stream>>>(
        cnt_s, offs_s, cnt_o, offs_o, partials, n, nblk_sc);
    k_scan_top<<<dim3(1), dim3(128), 0, stream>>>(partials, nblk_sc);
    k_scan_add<<<dim3(nblk_sc, 2), dim3(B), 0, stream>>>(
        offs_s, cur_s, offs_o, cur_o, partials, n, nblk_sc);
    k_latents<<<dim3((nm * 16 + B - 1) / B), dim3(B), 0, stream>>>(
        rel_emb, rm_rows, rm_cols, rm_vals, h_rows, v_cols,
        cur_s, cur_o, lat_s, lat_o, ou_s, su_o, nm);
    k_r0<<<dim3(64), dim3(B), 0, stream>>>(lat_s, rowsum, colsum, nt);
    k_latsum<<<dim3((n * 16 + B - 1) / B, 2), dim3(B), 0, stream>>>(
        lat_s, offs_s, cnt_s, rowsum, lat_o, offs_o, cnt_o, colsum, n);
    k_h_acc<<<dim3((n * 16 + B - 1) / B), dim3(B), 0, stream>>>(
        lat_o, offs_o, cnt_o, su_o, colsum, w1, h, n);
    k_h2<<<dim3(nblk_h2), dim3(B), 0, stream>>>(
        lat_s, offs_s, cnt_s, ou_s, rowsum, h, b1, h2, r0part, n);
    k_h2r0<<<dim3(1), dim3(1024), 0, stream>>>(r0part, h2, nblk_h2);
    k_out<<<dim3((n * 2 + B - 1) / B), dim3(B), 0, stream>>>(
        w2, b2, h2, (float*)d_out, n);
}

// Round 8
// 280.475 us; speedup vs baseline: 7.1425x; 1.0883x over previous
//
#include <hip/hip_runtime.h>

#define RP 16
#define EMB 16
#define NC 40

// ---------------------------------------------------------------------------
// Bucket counts per s and per o. (s_u is sorted, so cnt_s/offs_s describe
// contiguous t-runs; o-buckets need a real permutation.)
__global__ void k_count(const int* __restrict__ s_u, const int* __restrict__ o_u,
                        int* __restrict__ cnt_s, int* __restrict__ cnt_o, int nt) {
    int t = blockIdx.x * blockDim.x + threadIdx.x;
    if (t < nt) {
        atomicAdd(&cnt_s[s_u[t]], 1);
        atomicAdd(&cnt_o[o_u[t]], 1);
    }
}

// ---------------------------------------------------------------------------
// 3-phase hierarchical exclusive scan (2 arrays via blockIdx.y).
__global__ void k_scan_blk(const int* __restrict__ cnt_s, int* __restrict__ offs_s,
                           const int* __restrict__ cnt_o, int* __restrict__ offs_o,
                           int* __restrict__ partials, int n, int nblk) {
    const int* in = blockIdx.y ? cnt_o : cnt_s;
    int* out = blockIdx.y ? offs_o : offs_s;
    int tid = threadIdx.x;
    int i0 = blockIdx.x * 1024 + tid * 4;
    int v[4];
    #pragma unroll
    for (int q = 0; q < 4; ++q) {
        int i = i0 + q;
        v[q] = (i < n) ? in[i] : 0;
    }
    int tsum = v[0] + v[1] + v[2] + v[3];
    int lane = tid & 63, wid = tid >> 6;
    int x = tsum;
    #pragma unroll
    for (int d = 1; d < 64; d <<= 1) {
        int u = __shfl_up(x, d, 64);
        if (lane >= d) x += u;
    }
    __shared__ int wsum[4];
    if (lane == 63) wsum[wid] = x;
    __syncthreads();
    int woff = 0;
    for (int wq = 0; wq < wid; ++wq) woff += wsum[wq];
    int run = woff + x - tsum;
    #pragma unroll
    for (int q = 0; q < 4; ++q) {
        int i = i0 + q;
        if (i < n) out[i] = run;
        run += v[q];
    }
    if (tid == 255) partials[blockIdx.y * nblk + blockIdx.x] = run;
}

__global__ void k_scan_top(int* __restrict__ partials, int nblk) {
    int w = threadIdx.x >> 6;
    int lane = threadIdx.x & 63;
    int carry = 0;
    for (int base = 0; base < nblk; base += 64) {
        int idx = base + lane;
        int v = (idx < nblk) ? partials[w * nblk + idx] : 0;
        int x = v;
        #pragma unroll
        for (int d = 1; d < 64; d <<= 1) {
            int u = __shfl_up(x, d, 64);
            if (lane >= d) x += u;
        }
        if (idx < nblk) partials[w * nblk + idx] = carry + x - v;
        carry += __shfl(x, 63, 64);
    }
}

__global__ void k_scan_add(int* __restrict__ offs_s, int* __restrict__ cur_s,
                           int* __restrict__ offs_o, int* __restrict__ cur_o,
                           const int* __restrict__ partials, int n, int nblk) {
    int* out = blockIdx.y ? offs_o : offs_s;
    int* cur = blockIdx.y ? cur_o : cur_s;
    int add = partials[blockIdx.y * nblk + blockIdx.x];
    int i0 = blockIdx.x * 1024 + threadIdx.x * 4;
    #pragma unroll
    for (int q = 0; q < 4; ++q) {
        int i = i0 + q;
        if (i < n) {
            int vv = out[i] + add;
            out[i] = vv;
            cur[i] = vv;
        }
    }
}

// ---------------------------------------------------------------------------
// Fused: segment-sum over sorted rm_rows -> softmax ->
//   lat_t  : t-order (coalesced) == s-bucket order (s_u sorted!)
//   lat_o  : o-bucket order (cursor scatter), with su_o companion
//   lat0   : k=0 column in t-order (for the global r0 total)
__global__ void k_latents(const float* __restrict__ rel_emb,
                          const int* __restrict__ rows,
                          const int* __restrict__ cols,
                          const float* __restrict__ vals,
                          const int* __restrict__ s_u,
                          const int* __restrict__ o_u,
                          int* __restrict__ cur_o,
                          float* __restrict__ lat_t, float* __restrict__ lat_o,
                          float* __restrict__ lat0, int* __restrict__ su_o,
                          int nm) {
    int i = blockIdx.x * blockDim.x + threadIdx.x;
    int e = i >> 4, k = i & 15;
    if (e >= nm) return;
    int row = rows[e];
    if (e > 0 && rows[e - 1] == row) return;          // not a row leader
    float acc = vals[e] * rel_emb[cols[e] * RP + k];
    while (e + 1 < nm && rows[e + 1] == row) {
        ++e;
        acc += vals[e] * rel_emb[cols[e] * RP + k];
    }
    float m = acc;
    #pragma unroll
    for (int d = 1; d < 16; d <<= 1) m = fmaxf(m, __shfl_xor(m, d, 16));
    float v = expf(acc - m);
    float s = v;
    #pragma unroll
    for (int d = 1; d < 16; d <<= 1) s += __shfl_xor(s, d, 16);
    v = v / s;
    lat_t[(size_t)row * RP + k] = v;                  // coalesced
    int po = 0;
    if (k == 0) {
        int ou = o_u[row];
        po = atomicAdd(&cur_o[ou], 1);
        su_o[po] = s_u[row];
        lat0[row] = v;
    }
    po = __shfl(po, 0, 16);
    lat_o[(size_t)po * RP + k] = v;                   // scattered 64B row
}

// ---------------------------------------------------------------------------
// Global r0 total G = sum_t lat[t,0] -> rowsum[0], colsum[0].
__global__ void k_r0(const float* __restrict__ lat0,
                     float* __restrict__ rowsum, float* __restrict__ colsum,
                     int nt) {
    float acc = 0.f;
    for (int t = blockIdx.x * blockDim.x + threadIdx.x; t < nt;
         t += gridDim.x * blockDim.x)
        acc += lat0[t];
    #pragma unroll
    for (int d = 32; d; d >>= 1) acc += __shfl_down(acc, d, 64);
    __shared__ float sm[4];
    int lane = threadIdx.x & 63, wid = threadIdx.x >> 6;
    if (lane == 0) sm[wid] = acc;
    __syncthreads();
    if (threadIdx.x == 0) {
        float tot = sm[0] + sm[1] + sm[2] + sm[3];
        atomicAdd(&rowsum[0], tot);
        atomicAdd(&colsum[0], tot);
    }
}

// ---------------------------------------------------------------------------
// colsum: per-o latent sums (linear bucket reads); aliased (v*k) atomics.
__global__ void k_latsum(const float* __restrict__ lat_o,
                         const int* __restrict__ offs_o,
                         const int* __restrict__ cnt_o,
                         float* __restrict__ colsum, int n) {
    int i = blockIdx.x * blockDim.x + threadIdx.x;
    int v = i >> 4, k = i & 15;
    if (v >= n) return;
    int beg = offs_o[v], d = cnt_o[v];
    if (d == 0) return;
    float ls = 0.f;
    int j = 0;
    for (; j + 4 <= d; j += 4) {
        float a0 = lat_o[(size_t)(beg + j + 0) * RP + k];
        float a1 = lat_o[(size_t)(beg + j + 1) * RP + k];
        float a2 = lat_o[(size_t)(beg + j + 2) * RP + k];
        float a3 = lat_o[(size_t)(beg + j + 3) * RP + k];
        ls += (a0 + a1) + (a2 + a3);
    }
    for (; j < d; ++j) ls += lat_o[(size_t)(beg + j) * RP + k];
    if (k >= 1) atomicAdd(&colsum[(size_t)v * k], ls);
}

// ---------------------------------------------------------------------------
// Stage 4: per-o accumulation into raw h; linear bucket reads.
__global__ void k_h_acc(const float* __restrict__ lat_o,
                        const int* __restrict__ offs_o,
                        const int* __restrict__ cnt_o,
                        const int* __restrict__ su_o,
                        const float* __restrict__ colsum,
                        const float* __restrict__ w1,
                        float* __restrict__ h, int n) {
    int i = blockIdx.x * blockDim.x + threadIdx.x;
    int o = i >> 4, k = i & 15;
    if (o >= n) return;
    int d = cnt_o[o];
    if (d == 0) return;
    int beg = offs_o[o];
    float W[RP];
    #pragma unroll
    for (int r = 0; r < RP; ++r)
        W[r] = w1[(size_t)(o * r) * EMB + k];
    float rcp_cs = 1.f / colsum[(size_t)o * k];
    for (int j = 0; j < d; ++j) {
        float ln = lat_o[(size_t)(beg + j) * RP + k] * rcp_cs;
        int s = su_o[beg + j];
        float acc = 0.f;
        #pragma unroll
        for (int r = 0; r < RP; ++r)
            acc += __shfl(ln, r, 16) * W[r];
        atomicAdd(&h[s * EMB + k], acc);
    }
}

// ---------------------------------------------------------------------------
// Stage 5+6: per-s outer-product from t-ordered lat (contiguous run);
// bias+relu on h read; h2 written UNNORMALIZED; rowsum accumulated here.
__global__ void k_h2(const float* __restrict__ lat_t,
                     const int* __restrict__ offs_s,
                     const int* __restrict__ cnt_s,
                     const int* __restrict__ o_u,
                     float* __restrict__ rowsum,
                     const float* __restrict__ h,
                     const float* __restrict__ bias1,
                     float* __restrict__ h2,
                     float* __restrict__ r0part, int n) {
    __shared__ float r0acc[EMB];
    if (threadIdx.x < EMB) r0acc[threadIdx.x] = 0.f;
    __syncthreads();
    int i = blockIdx.x * blockDim.x + threadIdx.x;
    int s = i >> 4, k = i & 15;
    float b1k = bias1[k];
    float M[RP];
    #pragma unroll
    for (int r = 0; r < RP; ++r) M[r] = 0.f;
    float rs_acc = 0.f;
    int d = 0;
    if (s < n) {
        int beg = offs_s[s];
        d = cnt_s[s];
        for (int j = 0; j < d; ++j) {
            int o = o_u[beg + j];
            float hv = fmaxf(h[o * EMB + k] + b1k, 0.f);
            float lat = lat_t[(size_t)(beg + j) * RP + k];
            rs_acc += lat;
            #pragma unroll
            for (int r = 0; r < RP; ++r)
                M[r] += __shfl(lat, r, 16) * hv;
        }
    }
    if (s < n && d > 0) {
        if (k >= 1) atomicAdd(&rowsum[(size_t)s * k], rs_acc);
        atomicAdd(&r0acc[k], M[0]);
        #pragma unroll
        for (int r = 1; r < RP; ++r)
            atomicAdd(&h2[(size_t)(s * r) * EMB + k], M[r]);
    }
    __syncthreads();
    if (threadIdx.x < EMB)
        r0part[(size_t)blockIdx.x * EMB + threadIdx.x] = r0acc[threadIdx.x];
}

// Reduce r0part (nblk x 16) into h2[0:16]. One block of 1024.
__global__ void k_h2r0(const float* __restrict__ r0part,
                       float* __restrict__ h2, int nblk) {
    __shared__ float red[1024];
    int k = threadIdx.x & 15, j0 = threadIdx.x >> 4;   // j0 in [0,64)
    float acc = 0.f;
    for (int j = j0; j < nblk; j += 64)
        acc += r0part[(size_t)j * EMB + k];
    red[j0 * 16 + k] = acc;
    __syncthreads();
    #pragma unroll
    for (int st = 32; st >= 1; st >>= 1) {
        if (j0 < st) red[j0 * 16 + k] += red[(j0 + st) * 16 + k];
        __syncthreads();
    }
    if (threadIdx.x < 16) h2[threadIdx.x] += red[threadIdx.x];
}

// ---------------------------------------------------------------------------
// Stage 7: w2 staged in LDS; thread = (node, 20-col half).
// h2 rows normalized here by 1/rowsum[flat] (0-guarded).
#define CB2 20
__global__ void k_out(const float* __restrict__ w2,
                      const float* __restrict__ bias2,
                      const float* __restrict__ h2,
                      const float* __restrict__ rowsum,
                      float* __restrict__ out, int n) {
    __shared__ float w2s[RP * EMB * NC];          // 10240 floats = 40 KB
    for (int i = threadIdx.x; i < RP * EMB * NC; i += 256)
        w2s[i] = w2[i];
    __syncthreads();
    int gi = blockIdx.x * blockDim.x + threadIdx.x;
    int node = gi >> 1;
    int c0 = (gi & 1) * CB2;
    if (node >= n) return;
    float acc[CB2];
    #pragma unroll
    for (int c = 0; c < CB2; ++c) acc[c] = bias2[c0 + c];
    for (int rq = 0; rq < RP; ++rq) {
        size_t flat = (size_t)rq * n + node;
        float rs = rowsum[flat];
        float rcp = (rs != 0.f) ? 1.f / rs : 0.f;
        const float4* h2row = (const float4*)&h2[flat * EMB];
        float4 hv4[4];
        #pragma unroll
        for (int q = 0; q < 4; ++q) hv4[q] = h2row[q];
        const float* hv = (const float*)hv4;
        #pragma unroll
        for (int hh = 0; hh < EMB; ++hh) {
            const float4* wrow = (const float4*)&w2s[(rq * EMB + hh) * NC + c0];
            float hvv = hv[hh] * rcp;
            #pragma unroll
            for (int q5 = 0; q5 < 5; ++q5) {
                float4 wv = wrow[q5];
                acc[q5 * 4 + 0] += wv.x * hvv;
                acc[q5 * 4 + 1] += wv.y * hvv;
                acc[q5 * 4 + 2] += wv.z * hvv;
                acc[q5 * 4 + 3] += wv.w * hvv;
            }
        }
    }
    float4* op = (float4*)&out[node * NC + c0];
    #pragma unroll
    for (int q5 = 0; q5 < 5; ++q5)
        op[q5] = make_float4(acc[q5 * 4], acc[q5 * 4 + 1],
                             acc[q5 * 4 + 2], acc[q5 * 4 + 3]);
}

// ---------------------------------------------------------------------------
extern "C" void kernel_launch(void* const* d_in, const int* in_sizes, int n_in,
                              void* d_out, int out_size, void* d_ws, size_t ws_size,
                              hipStream_t stream) {
    const float* rel_emb = (const float*)d_in[0];
    const float* w1      = (const float*)d_in[1];
    const float* w2      = (const float*)d_in[2];
    const float* b1      = (const float*)d_in[3];
    const float* b2      = (const float*)d_in[4];
    const int*   rm_rows = (const int*)d_in[5];
    const int*   rm_cols = (const int*)d_in[6];
    const float* rm_vals = (const float*)d_in[7];
    const int*   h_rows  = (const int*)d_in[8];   // [0:nt] = s_u (sorted!)
    const int*   v_cols  = (const int*)d_in[11];  // [0:nt] = o_u

    const int nm = in_sizes[5];
    const int ne = in_sizes[8];
    const int nt = ne / RP;
    const int n  = in_sizes[1] / (RP * EMB);

    const int B = 256;
    const int nblk_h2 = (n * 16 + B - 1) / B;
    const int nblk_sc = (n + 1023) / 1024;

    char* w = (char*)d_ws;
    float* colsum = (float*)w;  w += (size_t)n * RP * 4;
    float* rowsum = (float*)w;  w += (size_t)n * RP * 4;
    float* h2     = (float*)w;  w += (size_t)n * RP * EMB * 4;
    float* h      = (float*)w;  w += (size_t)n * EMB * 4;
    int* cnt_s    = (int*)w;    w += (size_t)n * 4;
    int* cnt_o    = (int*)w;    w += (size_t)n * 4;
    size_t zero_bytes = (size_t)(w - (char*)d_ws);
    float* lat_t  = (float*)w;  w += (size_t)nt * RP * 4;
    float* lat_o  = (float*)w;  w += (size_t)nt * RP * 4;
    float* lat0   = (float*)w;  w += (size_t)nt * 4;
    int* su_o     = (int*)w;    w += (size_t)nt * 4;
    int* offs_s   = (int*)w;    w += (size_t)n * 4;
    int* cur_s    = (int*)w;    w += (size_t)n * 4;
    int* offs_o   = (int*)w;    w += (size_t)n * 4;
    int* cur_o    = (int*)w;    w += (size_t)n * 4;
    float* r0part = (float*)w;  w += (size_t)nblk_h2 * EMB * 4;
    int* partials = (int*)w;    w += (size_t)2 * nblk_sc * 4;
    if ((size_t)(w - (char*)d_ws) > ws_size) return;

    hipMemsetAsync(d_ws, 0, zero_bytes, stream);

    k_count<<<dim3((nt + B - 1) / B), dim3(B), 0, stream>>>(
        h_rows, v_cols, cnt_s, cnt_o, nt);
    k_scan_blk<<<dim3(nblk_sc, 2), dim3(B), 0, stream>>>(
        cnt_s, offs_s, cnt_o, offs_o, partials, n, nblk_sc);
    k_scan_top<<<dim3(1), dim3(128), 0, stream>>>(partials, nblk_sc);
    k_scan_add<<<dim3(nblk_sc, 2), dim3(B), 0, stream>>>(
        offs_s, cur_s, offs_o, cur_o, partials, n, nblk_sc);
    k_latents<<<dim3((nm * 16 + B - 1) / B), dim3(B), 0, stream>>>(
        rel_emb, rm_rows, rm_cols, rm_vals, h_rows, v_cols,
        cur_o, lat_t, lat_o, lat0, su_o, nm);
    k_r0<<<dim3(64), dim3(B), 0, stream>>>(lat0, rowsum, colsum, nt);
    k_latsum<<<dim3((n * 16 + B - 1) / B), dim3(B), 0, stream>>>(
        lat_o, offs_o, cnt_o, colsum, n);
    k_h_acc<<<dim3((n * 16 + B - 1) / B), dim3(B), 0, stream>>>(
        lat_o, offs_o, cnt_o, su_o, colsum, w1, h, n);
    k_h2<<<dim3(nblk_h2), dim3(B), 0, stream>>>(
        lat_t, offs_s, cnt_s, v_cols, rowsum, h, b1, h2, r0part, n);
    k_h2r0<<<dim3(1), dim3(1024), 0, stream>>>(r0part, h2, nblk_h2);
    k_out<<<dim3((n * 2 + B - 1) / B), dim3(B), 0, stream>>>(
        w2, b2, h2, rowsum, (float*)d_out, n);
}

// Round 9
// 277.177 us; speedup vs baseline: 7.2275x; 1.0119x over previous
//
#include <hip/hip_runtime.h>

#define RP 16
#define EMB 16
#define NC 40

// Broadcast lane R (0..15) of each 16-lane DPP row: v_mov_dpp row_newbcast:R.
// CDNA-only (gfx90a+), VALU-pipe, exact.
#define BCAST16(dst, srci, R) \
    dst = __int_as_float(__builtin_amdgcn_mov_dpp(srci, 0x150 + R, 0xf, 0xf, true));

// ---------------------------------------------------------------------------
// Bucket counts per s and per o. (s_u is sorted, so cnt_s/offs_s describe
// contiguous t-runs; o-buckets need a real permutation.)
__global__ void k_count(const int* __restrict__ s_u, const int* __restrict__ o_u,
                        int* __restrict__ cnt_s, int* __restrict__ cnt_o, int nt) {
    int t = blockIdx.x * blockDim.x + threadIdx.x;
    if (t < nt) {
        atomicAdd(&cnt_s[s_u[t]], 1);
        atomicAdd(&cnt_o[o_u[t]], 1);
    }
}

// ---------------------------------------------------------------------------
// 3-phase hierarchical exclusive scan (2 arrays via blockIdx.y).
__global__ void k_scan_blk(const int* __restrict__ cnt_s, int* __restrict__ offs_s,
                           const int* __restrict__ cnt_o, int* __restrict__ offs_o,
                           int* __restrict__ partials, int n, int nblk) {
    const int* in = blockIdx.y ? cnt_o : cnt_s;
    int* out = blockIdx.y ? offs_o : offs_s;
    int tid = threadIdx.x;
    int i0 = blockIdx.x * 1024 + tid * 4;
    int v[4];
    #pragma unroll
    for (int q = 0; q < 4; ++q) {
        int i = i0 + q;
        v[q] = (i < n) ? in[i] : 0;
    }
    int tsum = v[0] + v[1] + v[2] + v[3];
    int lane = tid & 63, wid = tid >> 6;
    int x = tsum;
    #pragma unroll
    for (int d = 1; d < 64; d <<= 1) {
        int u = __shfl_up(x, d, 64);
        if (lane >= d) x += u;
    }
    __shared__ int wsum[4];
    if (lane == 63) wsum[wid] = x;
    __syncthreads();
    int woff = 0;
    for (int wq = 0; wq < wid; ++wq) woff += wsum[wq];
    int run = woff + x - tsum;
    #pragma unroll
    for (int q = 0; q < 4; ++q) {
        int i = i0 + q;
        if (i < n) out[i] = run;
        run += v[q];
    }
    if (tid == 255) partials[blockIdx.y * nblk + blockIdx.x] = run;
}

__global__ void k_scan_top(int* __restrict__ partials, int nblk) {
    int w = threadIdx.x >> 6;
    int lane = threadIdx.x & 63;
    int carry = 0;
    for (int base = 0; base < nblk; base += 64) {
        int idx = base + lane;
        int v = (idx < nblk) ? partials[w * nblk + idx] : 0;
        int x = v;
        #pragma unroll
        for (int d = 1; d < 64; d <<= 1) {
            int u = __shfl_up(x, d, 64);
            if (lane >= d) x += u;
        }
        if (idx < nblk) partials[w * nblk + idx] = carry + x - v;
        carry += __shfl(x, 63, 64);
    }
}

__global__ void k_scan_add(int* __restrict__ offs_s, int* __restrict__ cur_s,
                           int* __restrict__ offs_o, int* __restrict__ cur_o,
                           const int* __restrict__ partials, int n, int nblk) {
    int* out = blockIdx.y ? offs_o : offs_s;
    int* cur = blockIdx.y ? cur_o : cur_s;
    int add = partials[blockIdx.y * nblk + blockIdx.x];
    int i0 = blockIdx.x * 1024 + threadIdx.x * 4;
    #pragma unroll
    for (int q = 0; q < 4; ++q) {
        int i = i0 + q;
        if (i < n) {
            int vv = out[i] + add;
            out[i] = vv;
            cur[i] = vv;
        }
    }
}

// ---------------------------------------------------------------------------
// Fused: segment-sum over sorted rm_rows -> softmax ->
//   lat_t  : t-order (coalesced) == s-bucket order (s_u sorted!)
//   lat_o  : o-bucket order (cursor scatter), with su_o companion
//   lat0   : k=0 column in t-order (for the global r0 total)
__global__ void k_latents(const float* __restrict__ rel_emb,
                          const int* __restrict__ rows,
                          const int* __restrict__ cols,
                          const float* __restrict__ vals,
                          const int* __restrict__ s_u,
                          const int* __restrict__ o_u,
                          int* __restrict__ cur_o,
                          float* __restrict__ lat_t, float* __restrict__ lat_o,
                          float* __restrict__ lat0, int* __restrict__ su_o,
                          int nm) {
    int i = blockIdx.x * blockDim.x + threadIdx.x;
    int e = i >> 4, k = i & 15;
    if (e >= nm) return;
    int row = rows[e];
    if (e > 0 && rows[e - 1] == row) return;          // not a row leader
    float acc = vals[e] * rel_emb[cols[e] * RP + k];
    while (e + 1 < nm && rows[e + 1] == row) {
        ++e;
        acc += vals[e] * rel_emb[cols[e] * RP + k];
    }
    float m = acc;
    #pragma unroll
    for (int d = 1; d < 16; d <<= 1) m = fmaxf(m, __shfl_xor(m, d, 16));
    float v = expf(acc - m);
    float s = v;
    #pragma unroll
    for (int d = 1; d < 16; d <<= 1) s += __shfl_xor(s, d, 16);
    v = v / s;
    lat_t[(size_t)row * RP + k] = v;                  // coalesced
    int po = 0;
    if (k == 0) {
        int ou = o_u[row];
        po = atomicAdd(&cur_o[ou], 1);
        su_o[po] = s_u[row];
        lat0[row] = v;
    }
    po = __shfl(po, 0, 16);
    lat_o[(size_t)po * RP + k] = v;                   // scattered 64B row
}

// ---------------------------------------------------------------------------
// Global r0 total G = sum_t lat[t,0] -> rowsum[0], colsum[0].
__global__ void k_r0(const float* __restrict__ lat0,
                     float* __restrict__ rowsum, float* __restrict__ colsum,
                     int nt) {
    float acc = 0.f;
    for (int t = blockIdx.x * blockDim.x + threadIdx.x; t < nt;
         t += gridDim.x * blockDim.x)
        acc += lat0[t];
    #pragma unroll
    for (int d = 32; d; d >>= 1) acc += __shfl_down(acc, d, 64);
    __shared__ float sm[4];
    int lane = threadIdx.x & 63, wid = threadIdx.x >> 6;
    if (lane == 0) sm[wid] = acc;
    __syncthreads();
    if (threadIdx.x == 0) {
        float tot = sm[0] + sm[1] + sm[2] + sm[3];
        atomicAdd(&rowsum[0], tot);
        atomicAdd(&colsum[0], tot);
    }
}

// ---------------------------------------------------------------------------
// colsum: per-o latent sums (linear bucket reads); aliased (v*k) atomics.
__global__ void k_latsum(const float* __restrict__ lat_o,
                         const int* __restrict__ offs_o,
                         const int* __restrict__ cnt_o,
                         float* __restrict__ colsum, int n) {
    int i = blockIdx.x * blockDim.x + threadIdx.x;
    int v = i >> 4, k = i & 15;
    if (v >= n) return;
    int beg = offs_o[v], d = cnt_o[v];
    if (d == 0) return;
    float ls = 0.f;
    int j = 0;
    for (; j + 4 <= d; j += 4) {
        float a0 = lat_o[(size_t)(beg + j + 0) * RP + k];
        float a1 = lat_o[(size_t)(beg + j + 1) * RP + k];
        float a2 = lat_o[(size_t)(beg + j + 2) * RP + k];
        float a3 = lat_o[(size_t)(beg + j + 3) * RP + k];
        ls += (a0 + a1) + (a2 + a3);
    }
    for (; j < d; ++j) ls += lat_o[(size_t)(beg + j) * RP + k];
    if (k >= 1) atomicAdd(&colsum[(size_t)v * k], ls);
}

// ---------------------------------------------------------------------------
// Stage 4: per-o accumulation into raw h; linear bucket reads.
// Inner broadcast via DPP row_newbcast (VALU) instead of ds_bpermute.
__global__ void k_h_acc(const float* __restrict__ lat_o,
                        const int* __restrict__ offs_o,
                        const int* __restrict__ cnt_o,
                        const int* __restrict__ su_o,
                        const float* __restrict__ colsum,
                        const float* __restrict__ w1,
                        float* __restrict__ h, int n) {
    int i = blockIdx.x * blockDim.x + threadIdx.x;
    int o = i >> 4, k = i & 15;
    if (o >= n) return;
    int d = cnt_o[o];
    if (d == 0) return;
    int beg = offs_o[o];
    float W[RP];
    #pragma unroll
    for (int r = 0; r < RP; ++r)
        W[r] = w1[(size_t)(o * r) * EMB + k];
    float rcp_cs = 1.f / colsum[(size_t)o * k];
    for (int j = 0; j < d; ++j) {
        float ln = lat_o[(size_t)(beg + j) * RP + k] * rcp_cs;
        int s = su_o[beg + j];
        int ln_i = __float_as_int(ln);
        float acc = 0.f, b;
        #define HACC_STEP(R) BCAST16(b, ln_i, R); acc = fmaf(b, W[R], acc);
        HACC_STEP(0)  HACC_STEP(1)  HACC_STEP(2)  HACC_STEP(3)
        HACC_STEP(4)  HACC_STEP(5)  HACC_STEP(6)  HACC_STEP(7)
        HACC_STEP(8)  HACC_STEP(9)  HACC_STEP(10) HACC_STEP(11)
        HACC_STEP(12) HACC_STEP(13) HACC_STEP(14) HACC_STEP(15)
        #undef HACC_STEP
        atomicAdd(&h[s * EMB + k], acc);
    }
}

// ---------------------------------------------------------------------------
// Stage 5+6: per-s outer-product from t-ordered lat (contiguous run);
// bias+relu on h read; h2 written UNNORMALIZED; rowsum accumulated here.
// Inner broadcast via DPP row_newbcast (VALU) instead of ds_bpermute.
__global__ void k_h2(const float* __restrict__ lat_t,
                     const int* __restrict__ offs_s,
                     const int* __restrict__ cnt_s,
                     const int* __restrict__ o_u,
                     float* __restrict__ rowsum,
                     const float* __restrict__ h,
                     const float* __restrict__ bias1,
                     float* __restrict__ h2,
                     float* __restrict__ r0part, int n) {
    __shared__ float r0acc[EMB];
    if (threadIdx.x < EMB) r0acc[threadIdx.x] = 0.f;
    __syncthreads();
    int i = blockIdx.x * blockDim.x + threadIdx.x;
    int s = i >> 4, k = i & 15;
    float b1k = bias1[k];
    float M[RP];
    #pragma unroll
    for (int r = 0; r < RP; ++r) M[r] = 0.f;
    float rs_acc = 0.f;
    int d = 0;
    if (s < n) {
        int beg = offs_s[s];
        d = cnt_s[s];
        for (int j = 0; j < d; ++j) {
            int o = o_u[beg + j];
            float hv = fmaxf(h[o * EMB + k] + b1k, 0.f);
            float lat = lat_t[(size_t)(beg + j) * RP + k];
            rs_acc += lat;
            int lat_i = __float_as_int(lat);
            float b;
            #define H2_STEP(R) BCAST16(b, lat_i, R); M[R] = fmaf(b, hv, M[R]);
            H2_STEP(0)  H2_STEP(1)  H2_STEP(2)  H2_STEP(3)
            H2_STEP(4)  H2_STEP(5)  H2_STEP(6)  H2_STEP(7)
            H2_STEP(8)  H2_STEP(9)  H2_STEP(10) H2_STEP(11)
            H2_STEP(12) H2_STEP(13) H2_STEP(14) H2_STEP(15)
            #undef H2_STEP
        }
    }
    if (s < n && d > 0) {
        if (k >= 1) atomicAdd(&rowsum[(size_t)s * k], rs_acc);
        atomicAdd(&r0acc[k], M[0]);
        #pragma unroll
        for (int r = 1; r < RP; ++r)
            atomicAdd(&h2[(size_t)(s * r) * EMB + k], M[r]);
    }
    __syncthreads();
    if (threadIdx.x < EMB)
        r0part[(size_t)blockIdx.x * EMB + threadIdx.x] = r0acc[threadIdx.x];
}

// Reduce r0part (nblk x 16) into h2[0:16]. One block of 1024.
__global__ void k_h2r0(const float* __restrict__ r0part,
                       float* __restrict__ h2, int nblk) {
    __shared__ float red[1024];
    int k = threadIdx.x & 15, j0 = threadIdx.x >> 4;   // j0 in [0,64)
    float acc = 0.f;
    for (int j = j0; j < nblk; j += 64)
        acc += r0part[(size_t)j * EMB + k];
    red[j0 * 16 + k] = acc;
    __syncthreads();
    #pragma unroll
    for (int st = 32; st >= 1; st >>= 1) {
        if (j0 < st) red[j0 * 16 + k] += red[(j0 + st) * 16 + k];
        __syncthreads();
    }
    if (threadIdx.x < 16) h2[threadIdx.x] += red[threadIdx.x];
}

// ---------------------------------------------------------------------------
// Stage 7: w2 staged in LDS; thread = (node, 20-col half).
// h2 rows normalized here by 1/rowsum[flat] (0-guarded).
#define CB2 20
__global__ void k_out(const float* __restrict__ w2,
                      const float* __restrict__ bias2,
                      const float* __restrict__ h2,
                      const float* __restrict__ rowsum,
                      float* __restrict__ out, int n) {
    __shared__ float w2s[RP * EMB * NC];          // 10240 floats = 40 KB
    for (int i = threadIdx.x; i < RP * EMB * NC; i += 256)
        w2s[i] = w2[i];
    __syncthreads();
    int gi = blockIdx.x * blockDim.x + threadIdx.x;
    int node = gi >> 1;
    int c0 = (gi & 1) * CB2;
    if (node >= n) return;
    float acc[CB2];
    #pragma unroll
    for (int c = 0; c < CB2; ++c) acc[c] = bias2[c0 + c];
    for (int rq = 0; rq < RP; ++rq) {
        size_t flat = (size_t)rq * n + node;
        float rs = rowsum[flat];
        float rcp = (rs != 0.f) ? 1.f / rs : 0.f;
        const float4* h2row = (const float4*)&h2[flat * EMB];
        float4 hv4[4];
        #pragma unroll
        for (int q = 0; q < 4; ++q) hv4[q] = h2row[q];
        const float* hv = (const float*)hv4;
        #pragma unroll
        for (int hh = 0; hh < EMB; ++hh) {
            const float4* wrow = (const float4*)&w2s[(rq * EMB + hh) * NC + c0];
            float hvv = hv[hh] * rcp;
            #pragma unroll
            for (int q5 = 0; q5 < 5; ++q5) {
                float4 wv = wrow[q5];
                acc[q5 * 4 + 0] += wv.x * hvv;
                acc[q5 * 4 + 1] += wv.y * hvv;
                acc[q5 * 4 + 2] += wv.z * hvv;
                acc[q5 * 4 + 3] += wv.w * hvv;
            }
        }
    }
    float4* op = (float4*)&out[node * NC + c0];
    #pragma unroll
    for (int q5 = 0; q5 < 5; ++q5)
        op[q5] = make_float4(acc[q5 * 4], acc[q5 * 4 + 1],
                             acc[q5 * 4 + 2], acc[q5 * 4 + 3]);
}

// ---------------------------------------------------------------------------
extern "C" void kernel_launch(void* const* d_in, const int* in_sizes, int n_in,
                              void* d_out, int out_size, void* d_ws, size_t ws_size,
                              hipStream_t stream) {
    const float* rel_emb = (const float*)d_in[0];
    const float* w1      = (const float*)d_in[1];
    const float* w2      = (const float*)d_in[2];
    const float* b1      = (const float*)d_in[3];
    const float* b2      = (const float*)d_in[4];
    const int*   rm_rows = (const int*)d_in[5];
    const int*   rm_cols = (const int*)d_in[6];
    const float* rm_vals = (const float*)d_in[7];
    const int*   h_rows  = (const int*)d_in[8];   // [0:nt] = s_u (sorted!)
    const int*   v_cols  = (const int*)d_in[11];  // [0:nt] = o_u

    const int nm = in_sizes[5];
    const int ne = in_sizes[8];
    const int nt = ne / RP;
    const int n  = in_sizes[1] / (RP * EMB);

    const int B = 256;
    const int nblk_h2 = (n * 16 + B - 1) / B;
    const int nblk_sc = (n + 1023) / 1024;

    char* w = (char*)d_ws;
    float* colsum = (float*)w;  w += (size_t)n * RP * 4;
    float* rowsum = (float*)w;  w += (size_t)n * RP * 4;
    float* h2     = (float*)w;  w += (size_t)n * RP * EMB * 4;
    float* h      = (float*)w;  w += (size_t)n * EMB * 4;
    int* cnt_s    = (int*)w;    w += (size_t)n * 4;
    int* cnt_o    = (int*)w;    w += (size_t)n * 4;
    size_t zero_bytes = (size_t)(w - (char*)d_ws);
    float* lat_t  = (float*)w;  w += (size_t)nt * RP * 4;
    float* lat_o  = (float*)w;  w += (size_t)nt * RP * 4;
    float* lat0   = (float*)w;  w += (size_t)nt * 4;
    int* su_o     = (int*)w;    w += (size_t)nt * 4;
    int* offs_s   = (int*)w;    w += (size_t)n * 4;
    int* cur_s    = (int*)w;    w += (size_t)n * 4;
    int* offs_o   = (int*)w;    w += (size_t)n * 4;
    int* cur_o    = (int*)w;    w += (size_t)n * 4;
    float* r0part = (float*)w;  w += (size_t)nblk_h2 * EMB * 4;
    int* partials = (int*)w;    w += (size_t)2 * nblk_sc * 4;
    if ((size_t)(w - (char*)d_ws) > ws_size) return;

    hipMemsetAsync(d_ws, 0, zero_bytes, stream);

    k_count<<<dim3((nt + B - 1) / B), dim3(B), 0, stream>>>(
        h_rows, v_cols, cnt_s, cnt_o, nt);
    k_scan_blk<<<dim3(nblk_sc, 2), dim3(B), 0, stream>>>(
        cnt_s, offs_s, cnt_o, offs_o, partials, n, nblk_sc);
    k_scan_top<<<dim3(1), dim3(128), 0, stream>>>(partials, nblk_sc);
    k_scan_add<<<dim3(nblk_sc, 2), dim3(B), 0, stream>>>(
        offs_s, cur_s, offs_o, cur_o, partials, n, nblk_sc);
    k_latents<<<dim3((nm * 16 + B - 1) / B), dim3(B), 0, stream>>>(
        rel_emb, rm_rows, rm_cols, rm_vals, h_rows, v_cols,
        cur_o, lat_t, lat_o, lat0, su_o, nm);
    k_r0<<<dim3(64), dim3(B), 0, stream>>>(lat0, rowsum, colsum, nt);
    k_latsum<<<dim3((n * 16 + B - 1) / B), dim3(B), 0, stream>>>(
        lat_o, offs_o, cnt_o, colsum, n);
    k_h_acc<<<dim3((n * 16 + B - 1) / B), dim3(B), 0, stream>>>(
        lat_o, offs_o, cnt_o, su_o, colsum, w1, h, n);
    k_h2<<<dim3(nblk_h2), dim3(B), 0, stream>>>(
        lat_t, offs_s, cnt_s, v_cols, rowsum, h, b1, h2, r0part, n);
    k_h2r0<<<dim3(1), dim3(1024), 0, stream>>>(r0part, h2, nblk_h2);
    k_out<<<dim3((n * 2 + B - 1) / B), dim3(B), 0, stream>>>(
        w2, b2, h2, rowsum, (float*)d_out, n);
}

// Round 11
// 270.334 us; speedup vs baseline: 7.4104x; 1.0253x over previous
//
#include <hip/hip_runtime.h>

#define RP 16
#define EMB 16
#define NC 40

// Broadcast lane R (0..15, compile-time constant) of each 16-lane DPP row.
#define BCASTF(dst, srci, R) \
    dst = __int_as_float(__builtin_amdgcn_mov_dpp(srci, 0x150 + R, 0xf, 0xf, true));

// ---------------------------------------------------------------------------
// Bucket counts per s and per o. (s_u is sorted, so cnt_s/offs_s describe
// contiguous t-runs; o-buckets need a real permutation.)
__global__ void k_count(const int* __restrict__ s_u, const int* __restrict__ o_u,
                        int* __restrict__ cnt_s, int* __restrict__ cnt_o, int nt) {
    int t = blockIdx.x * blockDim.x + threadIdx.x;
    if (t < nt) {
        atomicAdd(&cnt_s[s_u[t]], 1);
        atomicAdd(&cnt_o[o_u[t]], 1);
    }
}

// ---------------------------------------------------------------------------
// 3-phase hierarchical exclusive scan (2 arrays via blockIdx.y).
__global__ void k_scan_blk(const int* __restrict__ cnt_s, int* __restrict__ offs_s,
                           const int* __restrict__ cnt_o, int* __restrict__ offs_o,
                           int* __restrict__ partials, int n, int nblk) {
    const int* in = blockIdx.y ? cnt_o : cnt_s;
    int* out = blockIdx.y ? offs_o : offs_s;
    int tid = threadIdx.x;
    int i0 = blockIdx.x * 1024 + tid * 4;
    int v[4];
    #pragma unroll
    for (int q = 0; q < 4; ++q) {
        int i = i0 + q;
        v[q] = (i < n) ? in[i] : 0;
    }
    int tsum = v[0] + v[1] + v[2] + v[3];
    int lane = tid & 63, wid = tid >> 6;
    int x = tsum;
    #pragma unroll
    for (int d = 1; d < 64; d <<= 1) {
        int u = __shfl_up(x, d, 64);
        if (lane >= d) x += u;
    }
    __shared__ int wsum[4];
    if (lane == 63) wsum[wid] = x;
    __syncthreads();
    int woff = 0;
    for (int wq = 0; wq < wid; ++wq) woff += wsum[wq];
    int run = woff + x - tsum;
    #pragma unroll
    for (int q = 0; q < 4; ++q) {
        int i = i0 + q;
        if (i < n) out[i] = run;
        run += v[q];
    }
    if (tid == 255) partials[blockIdx.y * nblk + blockIdx.x] = run;
}

__global__ void k_scan_top(int* __restrict__ partials, int nblk) {
    int w = threadIdx.x >> 6;
    int lane = threadIdx.x & 63;
    int carry = 0;
    for (int base = 0; base < nblk; base += 64) {
        int idx = base + lane;
        int v = (idx < nblk) ? partials[w * nblk + idx] : 0;
        int x = v;
        #pragma unroll
        for (int d = 1; d < 64; d <<= 1) {
            int u = __shfl_up(x, d, 64);
            if (lane >= d) x += u;
        }
        if (idx < nblk) partials[w * nblk + idx] = carry + x - v;
        carry += __shfl(x, 63, 64);
    }
}

__global__ void k_scan_add(int* __restrict__ offs_s, int* __restrict__ cur_s,
                           int* __restrict__ offs_o, int* __restrict__ cur_o,
                           const int* __restrict__ partials, int n, int nblk) {
    int* out = blockIdx.y ? offs_o : offs_s;
    int* cur = blockIdx.y ? cur_o : cur_s;
    int add = partials[blockIdx.y * nblk + blockIdx.x];
    int i0 = blockIdx.x * 1024 + threadIdx.x * 4;
    #pragma unroll
    for (int q = 0; q < 4; ++q) {
        int i = i0 + q;
        if (i < n) {
            int vv = out[i] + add;
            out[i] = vv;
            cur[i] = vv;
        }
    }
}

// ---------------------------------------------------------------------------
// Fused: segment-sum over sorted rm_rows -> softmax ->
//   lat_t  : t-order (coalesced) == s-bucket order (s_u sorted!)
//   lat_o  : o-bucket order (cursor scatter), with su_o companion
//   lat0   : k=0 column in t-order (for the global r0 total)
__global__ void k_latents(const float* __restrict__ rel_emb,
                          const int* __restrict__ rows,
                          const int* __restrict__ cols,
                          const float* __restrict__ vals,
                          const int* __restrict__ s_u,
                          const int* __restrict__ o_u,
                          int* __restrict__ cur_o,
                          float* __restrict__ lat_t, float* __restrict__ lat_o,
                          float* __restrict__ lat0, int* __restrict__ su_o,
                          int nm) {
    int i = blockIdx.x * blockDim.x + threadIdx.x;
    int e = i >> 4, k = i & 15;
    if (e >= nm) return;
    int row = rows[e];
    if (e > 0 && rows[e - 1] == row) return;          // not a row leader
    float acc = vals[e] * rel_emb[cols[e] * RP + k];
    while (e + 1 < nm && rows[e + 1] == row) {
        ++e;
        acc += vals[e] * rel_emb[cols[e] * RP + k];
    }
    float m = acc;
    #pragma unroll
    for (int d = 1; d < 16; d <<= 1) m = fmaxf(m, __shfl_xor(m, d, 16));
    float v = expf(acc - m);
    float s = v;
    #pragma unroll
    for (int d = 1; d < 16; d <<= 1) s += __shfl_xor(s, d, 16);
    v = v / s;
    lat_t[(size_t)row * RP + k] = v;                  // coalesced
    int po = 0;
    if (k == 0) {
        int ou = o_u[row];
        po = atomicAdd(&cur_o[ou], 1);
        su_o[po] = s_u[row];
        lat0[row] = v;
    }
    po = __shfl(po, 0, 16);
    lat_o[(size_t)po * RP + k] = v;                   // scattered 64B row
}

// ---------------------------------------------------------------------------
// Global r0 total G = sum_t lat[t,0] -> rowsum[0], colsum[0].
__global__ void k_r0(const float* __restrict__ lat0,
                     float* __restrict__ rowsum, float* __restrict__ colsum,
                     int nt) {
    float acc = 0.f;
    for (int t = blockIdx.x * blockDim.x + threadIdx.x; t < nt;
         t += gridDim.x * blockDim.x)
        acc += lat0[t];
    #pragma unroll
    for (int d = 32; d; d >>= 1) acc += __shfl_down(acc, d, 64);
    __shared__ float sm[4];
    int lane = threadIdx.x & 63, wid = threadIdx.x >> 6;
    if (lane == 0) sm[wid] = acc;
    __syncthreads();
    if (threadIdx.x == 0) {
        float tot = sm[0] + sm[1] + sm[2] + sm[3];
        atomicAdd(&rowsum[0], tot);
        atomicAdd(&colsum[0], tot);
    }
}

// ---------------------------------------------------------------------------
// colsum: per-o latent sums (linear bucket reads); aliased (v*k) atomics.
__global__ void k_latsum(const float* __restrict__ lat_o,
                         const int* __restrict__ offs_o,
                         const int* __restrict__ cnt_o,
                         float* __restrict__ colsum, int n) {
    int i = blockIdx.x * blockDim.x + threadIdx.x;
    int v = i >> 4, k = i & 15;
    if (v >= n) return;
    int beg = offs_o[v], d = cnt_o[v];
    if (d == 0) return;
    float ls = 0.f;
    int j = 0;
    for (; j + 4 <= d; j += 4) {
        float a0 = lat_o[(size_t)(beg + j + 0) * RP + k];
        float a1 = lat_o[(size_t)(beg + j + 1) * RP + k];
        float a2 = lat_o[(size_t)(beg + j + 2) * RP + k];
        float a3 = lat_o[(size_t)(beg + j + 3) * RP + k];
        ls += (a0 + a1) + (a2 + a3);
    }
    for (; j < d; ++j) ls += lat_o[(size_t)(beg + j) * RP + k];
    if (k >= 1) atomicAdd(&colsum[(size_t)v * k], ls);
}

// ---------------------------------------------------------------------------
// Stage 4: per-o accumulation into raw h. Chunk-16: preload su/lat (coalesced,
// all in flight), then masked compute + atomic. Runtime-lane broadcasts via
// __shfl (off the FMA critical path); FMA-path broadcasts via literal DPP.
__global__ void k_h_acc(const float* __restrict__ lat_o,
                        const int* __restrict__ offs_o,
                        const int* __restrict__ cnt_o,
                        const int* __restrict__ su_o,
                        const float* __restrict__ colsum,
                        const float* __restrict__ w1,
                        float* __restrict__ h, int n) {
    int i = blockIdx.x * blockDim.x + threadIdx.x;
    int o = i >> 4, k = i & 15;
    if (o >= n) return;
    int d = cnt_o[o];
    if (d == 0) return;
    int beg = offs_o[o];
    float W[RP];
    #pragma unroll
    for (int r = 0; r < RP; ++r)
        W[r] = w1[(size_t)(o * r) * EMB + k];
    float rcp_cs = 1.f / colsum[(size_t)o * k];
    for (int j0 = 0; j0 < d; j0 += 16) {
        int su16 = su_o[beg + min(j0 + k, d - 1)];    // lane k: entry j0+k
        float la[16];
        #pragma unroll
        for (int e = 0; e < 16; ++e)
            la[e] = lat_o[(size_t)(beg + min(j0 + e, d - 1)) * RP + k];
        #pragma unroll
        for (int e = 0; e < 16; ++e) {
            if (j0 + e >= d) break;                   // uniform across group
            float ln = la[e] * rcp_cs;
            int ln_i = __float_as_int(ln);
            float acc = 0.f, b;
            #define HACC_STEP(R) BCASTF(b, ln_i, R); acc = fmaf(b, W[R], acc);
            HACC_STEP(0)  HACC_STEP(1)  HACC_STEP(2)  HACC_STEP(3)
            HACC_STEP(4)  HACC_STEP(5)  HACC_STEP(6)  HACC_STEP(7)
            HACC_STEP(8)  HACC_STEP(9)  HACC_STEP(10) HACC_STEP(11)
            HACC_STEP(12) HACC_STEP(13) HACC_STEP(14) HACC_STEP(15)
            #undef HACC_STEP
            int s = __shfl(su16, e, 16);
            atomicAdd(&h[s * EMB + k], acc);
        }
    }
}

// ---------------------------------------------------------------------------
// Stage 5+6: per-s outer-product. Chunk-16: preload o-indices (coalesced),
// then 16 independent h-row gathers + lat loads in flight; masked compute.
// h2 written UNNORMALIZED; rowsum accumulated here.
__global__ void k_h2(const float* __restrict__ lat_t,
                     const int* __restrict__ offs_s,
                     const int* __restrict__ cnt_s,
                     const int* __restrict__ o_u,
                     float* __restrict__ rowsum,
                     const float* __restrict__ h,
                     const float* __restrict__ bias1,
                     float* __restrict__ h2,
                     float* __restrict__ r0part, int n) {
    __shared__ float r0acc[EMB];
    if (threadIdx.x < EMB) r0acc[threadIdx.x] = 0.f;
    __syncthreads();
    int i = blockIdx.x * blockDim.x + threadIdx.x;
    int s = i >> 4, k = i & 15;
    float b1k = bias1[k];
    float M[RP];
    #pragma unroll
    for (int r = 0; r < RP; ++r) M[r] = 0.f;
    float rs_acc = 0.f;
    int d = 0;
    if (s < n) {
        int beg = offs_s[s];
        d = cnt_s[s];
        for (int j0 = 0; j0 < d; j0 += 16) {
            int o16 = o_u[beg + min(j0 + k, d - 1)];  // lane k: entry j0+k
            float hv[16], la[16];
            #pragma unroll
            for (int e = 0; e < 16; ++e) {
                int oe = __shfl(o16, e, 16);
                hv[e] = h[(size_t)oe * EMB + k];      // coalesced 64B row
                la[e] = lat_t[(size_t)(beg + min(j0 + e, d - 1)) * RP + k];
            }
            #pragma unroll
            for (int e = 0; e < 16; ++e) {
                if (j0 + e >= d) break;               // uniform across group
                float hvr = fmaxf(hv[e] + b1k, 0.f);
                rs_acc += la[e];
                int lat_i = __float_as_int(la[e]);
                float b;
                #define H2_STEP(R) BCASTF(b, lat_i, R); M[R] = fmaf(b, hvr, M[R]);
                H2_STEP(0)  H2_STEP(1)  H2_STEP(2)  H2_STEP(3)
                H2_STEP(4)  H2_STEP(5)  H2_STEP(6)  H2_STEP(7)
                H2_STEP(8)  H2_STEP(9)  H2_STEP(10) H2_STEP(11)
                H2_STEP(12) H2_STEP(13) H2_STEP(14) H2_STEP(15)
                #undef H2_STEP
            }
        }
    }
    if (s < n && d > 0) {
        if (k >= 1) atomicAdd(&rowsum[(size_t)s * k], rs_acc);
        atomicAdd(&r0acc[k], M[0]);
        #pragma unroll
        for (int r = 1; r < RP; ++r)
            atomicAdd(&h2[(size_t)(s * r) * EMB + k], M[r]);
    }
    __syncthreads();
    if (threadIdx.x < EMB)
        r0part[(size_t)blockIdx.x * EMB + threadIdx.x] = r0acc[threadIdx.x];
}

// Reduce r0part (nblk x 16) into h2[0:16]. One block of 1024.
__global__ void k_h2r0(const float* __restrict__ r0part,
                       float* __restrict__ h2, int nblk) {
    __shared__ float red[1024];
    int k = threadIdx.x & 15, j0 = threadIdx.x >> 4;   // j0 in [0,64)
    float acc = 0.f;
    for (int j = j0; j < nblk; j += 64)
        acc += r0part[(size_t)j * EMB + k];
    red[j0 * 16 + k] = acc;
    __syncthreads();
    #pragma unroll
    for (int st = 32; st >= 1; st >>= 1) {
        if (j0 < st) red[j0 * 16 + k] += red[(j0 + st) * 16 + k];
        __syncthreads();
    }
    if (threadIdx.x < 16) h2[threadIdx.x] += red[threadIdx.x];
}

// ---------------------------------------------------------------------------
// Stage 7: w2 staged in LDS; thread = (node, 20-col half).
// h2 rows normalized here by 1/rowsum[flat] (0-guarded).
#define CB2 20
__global__ void k_out(const float* __restrict__ w2,
                      const float* __restrict__ bias2,
                      const float* __restrict__ h2,
                      const float* __restrict__ rowsum,
                      float* __restrict__ out, int n) {
    __shared__ float w2s[RP * EMB * NC];          // 10240 floats = 40 KB
    for (int i = threadIdx.x; i < RP * EMB * NC; i += 256)
        w2s[i] = w2[i];
    __syncthreads();
    int gi = blockIdx.x * blockDim.x + threadIdx.x;
    int node = gi >> 1;
    int c0 = (gi & 1) * CB2;
    if (node >= n) return;
    float acc[CB2];
    #pragma unroll
    for (int c = 0; c < CB2; ++c) acc[c] = bias2[c0 + c];
    for (int rq = 0; rq < RP; ++rq) {
        size_t flat = (size_t)rq * n + node;
        float rs = rowsum[flat];
        float rcp = (rs != 0.f) ? 1.f / rs : 0.f;
        const float4* h2row = (const float4*)&h2[flat * EMB];
        float4 hv4[4];
        #pragma unroll
        for (int q = 0; q < 4; ++q) hv4[q] = h2row[q];
        const float* hv = (const float*)hv4;
        #pragma unroll
        for (int hh = 0; hh < EMB; ++hh) {
            const float4* wrow = (const float4*)&w2s[(rq * EMB + hh) * NC + c0];
            float hvv = hv[hh] * rcp;
            #pragma unroll
            for (int q5 = 0; q5 < 5; ++q5) {
                float4 wv = wrow[q5];
                acc[q5 * 4 + 0] += wv.x * hvv;
                acc[q5 * 4 + 1] += wv.y * hvv;
                acc[q5 * 4 + 2] += wv.z * hvv;
                acc[q5 * 4 + 3] += wv.w * hvv;
            }
        }
    }
    float4* op = (float4*)&out[node * NC + c0];
    #pragma unroll
    for (int q5 = 0; q5 < 5; ++q5)
        op[q5] = make_float4(acc[q5 * 4], acc[q5 * 4 + 1],
                             acc[q5 * 4 + 2], acc[q5 * 4 + 3]);
}

// ---------------------------------------------------------------------------
extern "C" void kernel_launch(void* const* d_in, const int* in_sizes, int n_in,
                              void* d_out, int out_size, void* d_ws, size_t ws_size,
                              hipStream_t stream) {
    const float* rel_emb = (const float*)d_in[0];
    const float* w1      = (const float*)d_in[1];
    const float* w2      = (const float*)d_in[2];
    const float* b1      = (const float*)d_in[3];
    const float* b2      = (const float*)d_in[4];
    const int*   rm_rows = (const int*)d_in[5];
    const int*   rm_cols = (const int*)d_in[6];
    const float* rm_vals = (const float*)d_in[7];
    const int*   h_rows  = (const int*)d_in[8];   // [0:nt] = s_u (sorted!)
    const int*   v_cols  = (const int*)d_in[11];  // [0:nt] = o_u

    const int nm = in_sizes[5];
    const int ne = in_sizes[8];
    const int nt = ne / RP;
    const int n  = in_sizes[1] / (RP * EMB);

    const int B = 256;
    const int nblk_h2 = (n * 16 + B - 1) / B;
    const int nblk_sc = (n + 1023) / 1024;

    char* w = (char*)d_ws;
    float* colsum = (float*)w;  w += (size_t)n * RP * 4;
    float* rowsum = (float*)w;  w += (size_t)n * RP * 4;
    float* h2     = (float*)w;  w += (size_t)n * RP * EMB * 4;
    float* h      = (float*)w;  w += (size_t)n * EMB * 4;
    int* cnt_s    = (int*)w;    w += (size_t)n * 4;
    int* cnt_o    = (int*)w;    w += (size_t)n * 4;
    size_t zero_bytes = (size_t)(w - (char*)d_ws);
    float* lat_t  = (float*)w;  w += (size_t)nt * RP * 4;
    float* lat_o  = (float*)w;  w += (size_t)nt * RP * 4;
    float* lat0   = (float*)w;  w += (size_t)nt * 4;
    int* su_o     = (int*)w;    w += (size_t)nt * 4;
    int* offs_s   = (int*)w;    w += (size_t)n * 4;
    int* cur_s    = (int*)w;    w += (size_t)n * 4;
    int* offs_o   = (int*)w;    w += (size_t)n * 4;
    int* cur_o    = (int*)w;    w += (size_t)n * 4;
    float* r0part = (float*)w;  w += (size_t)nblk_h2 * EMB * 4;
    int* partials = (int*)w;    w += (size_t)2 * nblk_sc * 4;
    if ((size_t)(w - (char*)d_ws) > ws_size) return;

    hipMemsetAsync(d_ws, 0, zero_bytes, stream);

    k_count<<<dim3((nt + B - 1) / B), dim3(B), 0, stream>>>(
        h_rows, v_cols, cnt_s, cnt_o, nt);
    k_scan_blk<<<dim3(nblk_sc, 2), dim3(B), 0, stream>>>(
        cnt_s, offs_s, cnt_o, offs_o, partials, n, nblk_sc);
    k_scan_top<<<dim3(1), dim3(128), 0, stream>>>(partials, nblk_sc);
    k_scan_add<<<dim3(nblk_sc, 2), dim3(B), 0, stream>>>(
        offs_s, cur_s, offs_o, cur_o, partials, n, nblk_sc);
    k_latents<<<dim3((nm * 16 + B - 1) / B), dim3(B), 0, stream>>>(
        rel_emb, rm_rows, rm_cols, rm_vals, h_rows, v_cols,
        cur_o, lat_t, lat_o, lat0, su_o, nm);
    k_r0<<<dim3(64), dim3(B), 0, stream>>>(lat0, rowsum, colsum, nt);
    k_latsum<<<dim3((n * 16 + B - 1) / B), dim3(B), 0, stream>>>(
        lat_o, offs_o, cnt_o, colsum, n);
    k_h_acc<<<dim3((n * 16 + B - 1) / B), dim3(B), 0, stream>>>(
        lat_o, offs_o, cnt_o, su_o, colsum, w1, h, n);
    k_h2<<<dim3(nblk_h2), dim3(B), 0, stream>>>(
        lat_t, offs_s, cnt_s, v_cols, rowsum, h, b1, h2, r0part, n);
    k_h2r0<<<dim3(1), dim3(1024), 0, stream>>>(r0part, h2, nblk_h2);
    k_out<<<dim3((n * 2 + B - 1) / B), dim3(B), 0, stream>>>(
        w2, b2, h2, rowsum, (float*)d_out, n);
}